// Round 3
// baseline (319.866 us; speedup 1.0000x reference)
//
#include <hip/hip_runtime.h>
#include <hip/hip_bf16.h>
#include <math.h>

#define TT 2048
#define HH 2048
#define EE 8
#define II 1408

typedef short bf16x8 __attribute__((ext_vector_type(8)));
typedef float f32x4 __attribute__((ext_vector_type(4)));
typedef unsigned int u32;
typedef unsigned short u16;

__device__ __forceinline__ u16 f2bf(float f) {
  union { float f; u32 u; } v; v.f = f;
  u32 r = v.u + 0x7fffu + ((v.u >> 16) & 1u);
  return (u16)(r >> 16);
}

__device__ __forceinline__ void gload16(const void* g, void* l) {
  __builtin_amdgcn_global_load_lds((const __attribute__((address_space(1))) u32*)g,
                                   (__attribute__((address_space(3))) u32*)l, 16, 0, 0);
}

// ---------------- zero out (+ optional midF) + counters ----------------
__global__ void zero_kernel(float4* __restrict__ out4, int n4,
                            float4* __restrict__ midF4, int nmid4,
                            int* __restrict__ counts) {
  int i = blockIdx.x * blockDim.x + threadIdx.x;
  int stride = gridDim.x * blockDim.x;
  float4 z; z.x = 0.f; z.y = 0.f; z.z = 0.f; z.w = 0.f;
  for (int j = i; j < n4; j += stride) out4[j] = z;
  if (midF4) for (int j = i; j < nmid4; j += stride) midF4[j] = z;
  if (blockIdx.x == 0 && threadIdx.x < 2 * EE) counts[threadIdx.x] = 0;
}

// ---------------- router ----------------
__global__ void router_kernel(const float* __restrict__ x, const float* __restrict__ gw,
                              int* __restrict__ tk_id, float* __restrict__ tk_w,
                              int* __restrict__ counts) {
  int t = blockIdx.x;
  int lane = threadIdx.x;
  float acc[EE];
#pragma unroll
  for (int e = 0; e < EE; ++e) acc[e] = 0.f;
  const float* xr = x + (size_t)t * HH;
  for (int h = lane; h < HH; h += 64) {
    float xv = xr[h];
    const float* g = gw + (size_t)h * EE;
#pragma unroll
    for (int e = 0; e < EE; ++e) acc[e] += xv * g[e];
  }
#pragma unroll
  for (int off = 32; off > 0; off >>= 1) {
#pragma unroll
    for (int e = 0; e < EE; ++e) acc[e] += __shfl_down(acc[e], off, 64);
  }
  if (lane == 0) {
    int i0 = 0;
#pragma unroll
    for (int e = 1; e < EE; ++e) if (acc[e] > acc[i0]) i0 = e;
    int i1 = (i0 == 0) ? 1 : 0;
#pragma unroll
    for (int e = 0; e < EE; ++e) { if (e == i0) continue; if (acc[e] > acc[i1]) i1 = e; }
    float d = acc[i1] - acc[i0];
    float p1 = expf(d);
    float w0 = 1.f / (1.f + p1);
    float w1v = p1 * w0;
    tk_id[2 * t] = i0; tk_id[2 * t + 1] = i1;
    tk_w[2 * t] = w0;  tk_w[2 * t + 1] = w1v;
    atomicAdd(&counts[i0], 1);
    atomicAdd(&counts[i1], 1);
  }
}

// ---------------- scan ----------------
__global__ void scan_kernel(const int* __restrict__ counts, int* __restrict__ offsets,
                            int* __restrict__ cursor) {
  if (threadIdx.x == 0) {
    int s = 0;
    for (int e = 0; e < EE; ++e) { offsets[e] = s; s += counts[e]; cursor[e] = 0; }
    offsets[EE] = s;
  }
}

// ---------------- assign ----------------
__global__ void assign_kernel(const int* __restrict__ tk_id, const float* __restrict__ tk_w,
                              const int* __restrict__ offsets, int* __restrict__ cursor,
                              int* __restrict__ tok_list, float* __restrict__ wt_list) {
  int t = blockIdx.x * blockDim.x + threadIdx.x;
  if (t >= TT) return;
#pragma unroll
  for (int k = 0; k < 2; ++k) {
    int e = tk_id[2 * t + k];
    int p = atomicAdd(&cursor[e], 1);
    int slot = offsets[e] + p;
    tok_list[slot] = t;
    wt_list[slot] = tk_w[2 * t + k];
  }
}

// ---------------- gather x -> bf16 xg[slot][H] ----------------
__global__ void gather_x_kernel(const float* __restrict__ x, const int* __restrict__ tok_list,
                                u16* __restrict__ xg) {
  int slot = blockIdx.x;
  int tok = tok_list[slot];
  int c = threadIdx.x * 8;
  float4 v0 = *(const float4*)(x + (size_t)tok * HH + c);
  float4 v1 = *(const float4*)(x + (size_t)tok * HH + c + 4);
  u16 o[8] = { f2bf(v0.x), f2bf(v0.y), f2bf(v0.z), f2bf(v0.w),
               f2bf(v1.x), f2bf(v1.y), f2bf(v1.z), f2bf(v1.w) };
  *(uint4*)(xg + (size_t)slot * HH + c) = *(uint4*)o;
}

// ---------------- convert + transpose: w[e][K][N] fp32 -> wb[e][N][K] bf16 ----------------
__global__ void convtrans_kernel(const float* __restrict__ w, u16* __restrict__ wb,
                                 int K, int N) {
  int e = blockIdx.z;
  int n0 = blockIdx.x * 64, k0 = blockIdx.y * 64;
  __shared__ u16 sT[64][72];
  const float* we = w + (size_t)e * K * N;
  u16* wbe = wb + (size_t)e * K * N;
  int tid = threadIdx.x;
  int kl = tid >> 4, n4 = tid & 15;
#pragma unroll
  for (int j = 0; j < 4; ++j) {
    int k = kl + j * 16;
    float4 v = *(const float4*)(we + (size_t)(k0 + k) * N + n0 + n4 * 4);
    sT[n4 * 4 + 0][k] = f2bf(v.x);
    sT[n4 * 4 + 1][k] = f2bf(v.y);
    sT[n4 * 4 + 2][k] = f2bf(v.z);
    sT[n4 * 4 + 3][k] = f2bf(v.w);
  }
  __syncthreads();
  int nl = tid >> 3, kc = tid & 7;
#pragma unroll
  for (int j = 0; j < 2; ++j) {
    int n = nl + j * 32;
    uint4 v = *(const uint4*)(&sT[n][kc * 8]);
    *(uint4*)(wbe + (size_t)(n0 + n) * K + k0 + kc * 8) = v;
  }
}

// ---------------- silu + convert: midF f32 -> midB bf16 ----------------
__global__ void silu_kernel(const float* __restrict__ midF, u16* __restrict__ midB, int n8) {
  int i = blockIdx.x * blockDim.x + threadIdx.x;
  int stride = gridDim.x * blockDim.x;
  for (int j = i; j < n8; j += stride) {
    float4 a = *(const float4*)(midF + (size_t)j * 8);
    float4 b = *(const float4*)(midF + (size_t)j * 8 + 4);
    float vv[8] = { a.x, a.y, a.z, a.w, b.x, b.y, b.z, b.w };
    u16 o[8];
#pragma unroll
    for (int q = 0; q < 8; ++q) {
      float v = vv[q];
      o[q] = f2bf(v / (1.f + expf(-v)));
    }
    *(uint4*)(midB + (size_t)j * 8) = *(uint4*)o;
  }
}

// ---------------- grouped GEMM, 128x128x64, dbuf 2-phase, gload_lds + XOR swizzle ----------------
// A: [slot][KDIM] bf16; B: [e][Ndim][KDIM] bf16 (N-major).
// MODE 0: silu -> midB direct (KS must be 1)
// MODE 1: atomicAdd fp32 into midF (K-split gemm1)
// MODE 2: atomicAdd wt-scaled into out (gemm2)
template <int KDIM, int KS, int MODE>
__launch_bounds__(256)
__global__ void moe_gemm(const u16* __restrict__ A, const u16* __restrict__ B,
                         const int* __restrict__ tok_list, const float* __restrict__ wt_list,
                         const int* __restrict__ offsets,
                         u16* __restrict__ midB, float* __restrict__ midF,
                         float* __restrict__ out) {
  constexpr int Ndim = (MODE == 2) ? HH : II;
  constexpr int NCB = Ndim / 128;
  constexpr int KLEN = KDIM / KS;
  constexpr int NT = KLEN / 64;

  int e = blockIdx.x;                 // expert = fastest dim -> XCD = e (L2 locality)
  int g_off = offsets[e];
  int n_e = offsets[e + 1] - g_off;
  int row0 = blockIdx.z * 128;
  if (row0 >= n_e) return;
  int cb = blockIdx.y % NCB;
  int ks = blockIdx.y / NCB;
  int n0 = cb * 128;
  int k_beg = ks * KLEN;

  __shared__ u16 sA[2][128][64];
  __shared__ u16 sB[2][128][64];
  __shared__ int s_tok[128];
  __shared__ float s_wt[128];

  int tid = threadIdx.x;
  int lane = tid & 63, wv = tid >> 6;
  int wm = wv >> 1, wn = wv & 1;
  int fr = lane & 15, kg = lane >> 4;

  if constexpr (MODE == 2) {
    if (tid < 128) {
      int r = row0 + tid;
      int cr = r < n_e ? r : n_e - 1;
      s_tok[tid] = tok_list[g_off + cr];
      s_wt[tid] = wt_list[g_off + cr];
    }
  }

  // staging: lane l writes 16B at LDS chunk base + l*16; chunk c = j*4 + wv = 8 rows.
  // global source col pre-swizzled (XOR involution) to match swizzled ds_read.
  int rA = lane >> 3;
  int colsw = ((lane & 7) ^ rA) * 8;
  const u16* Abase = A + (size_t)(g_off + row0 + rA) * KDIM + k_beg + colsw;
  const u16* Bbase = B + (size_t)e * (size_t)Ndim * KDIM + (size_t)(n0 + rA) * KDIM + k_beg + colsw;

  f32x4 acc[4][4];
#pragma unroll
  for (int m = 0; m < 4; ++m)
#pragma unroll
    for (int n = 0; n < 4; ++n)
      acc[m][n] = (f32x4){0.f, 0.f, 0.f, 0.f};

  // prologue: stage tile 0 into buf 0
#pragma unroll
  for (int j = 0; j < 4; ++j) {
    int c = j * 4 + wv;
    gload16(Abase + (size_t)c * 8 * KDIM, &sA[0][c * 8][0]);
    gload16(Bbase + (size_t)c * 8 * KDIM, &sB[0][c * 8][0]);
  }
  __syncthreads();   // compiler drains vmcnt(0) before barrier

  for (int t = 0; t < NT; ++t) {
    int cur = t & 1;
    if (t + 1 < NT) {
      int kof = (t + 1) * 64;
#pragma unroll
      for (int j = 0; j < 4; ++j) {
        int c = j * 4 + wv;
        gload16(Abase + (size_t)c * 8 * KDIM + kof, &sA[cur ^ 1][c * 8][0]);
        gload16(Bbase + (size_t)c * 8 * KDIM + kof, &sB[cur ^ 1][c * 8][0]);
      }
    }
#pragma unroll
    for (int kh = 0; kh < 2; ++kh) {
      bf16x8 af[4], bg[4];
      int cbyte = (kh * 64 + kg * 16) ^ ((fr & 7) << 4);
#pragma unroll
      for (int m = 0; m < 4; ++m)
        af[m] = *(const bf16x8*)((const char*)&sA[cur][0][0] + (wm * 64 + m * 16 + fr) * 128 + cbyte);
#pragma unroll
      for (int n = 0; n < 4; ++n)
        bg[n] = *(const bf16x8*)((const char*)&sB[cur][0][0] + (wn * 64 + n * 16 + fr) * 128 + cbyte);
#pragma unroll
      for (int m = 0; m < 4; ++m)
#pragma unroll
        for (int n = 0; n < 4; ++n)
          acc[m][n] = __builtin_amdgcn_mfma_f32_16x16x32_bf16(af[m], bg[n], acc[m][n], 0, 0, 0);
    }
    __syncthreads();   // next-tile stage landed; buf[cur] free for overwrite next iter
  }

#pragma unroll
  for (int m = 0; m < 4; ++m) {
    int lr = wm * 64 + m * 16 + kg * 4;
#pragma unroll
    for (int n = 0; n < 4; ++n) {
      int lc = wn * 64 + n * 16 + fr;
#pragma unroll
      for (int r = 0; r < 4; ++r) {
        int rr = lr + r;
        if (row0 + rr < n_e) {
          if constexpr (MODE == 0) {
            float v = acc[m][n][r];
            float s = v / (1.f + expf(-v));
            midB[(size_t)(g_off + row0 + rr) * II + n0 + lc] = f2bf(s);
          } else if constexpr (MODE == 1) {
            atomicAdd(midF + (size_t)(g_off + row0 + rr) * II + n0 + lc, acc[m][n][r]);
          } else {
            float v = acc[m][n][r] * s_wt[rr];
            atomicAdd(out + (size_t)s_tok[rr] * HH + n0 + lc, v);
          }
        }
      }
    }
  }
}

// ================= small fallback (round-1, proven) =================
__launch_bounds__(256, 2)
__global__ void gemm1_small(const float* __restrict__ x, const float* __restrict__ w1,
                            const int* __restrict__ tok_list, const int* __restrict__ offsets,
                            u16* __restrict__ mid) {
  int e = blockIdx.z;
  int g_off = offsets[e];
  int n_e = offsets[e + 1] - g_off;
  int row0 = blockIdx.y * 64;
  if (row0 >= n_e) return;
  int n0 = blockIdx.x * 64;
  __shared__ u16 sA[64][72];
  __shared__ u16 sB[64][72];
  __shared__ int s_tok[64];
  int tid = threadIdx.x;
  if (tid < 64) {
    int r = row0 + tid;
    s_tok[tid] = tok_list[g_off + ((r < n_e) ? r : (n_e - 1))];
  }
  __syncthreads();
  int lane = tid & 63;
  int wv = tid >> 6;
  int wm = wv >> 1, wn = wv & 1;
  int fr = lane & 15, kg = lane >> 4;
  f32x4 acc[2][2];
#pragma unroll
  for (int i = 0; i < 2; ++i)
#pragma unroll
    for (int j = 0; j < 2; ++j) acc[i][j] = (f32x4){0.f, 0.f, 0.f, 0.f};
  const float* w1e = w1 + (size_t)e * HH * II;
  for (int k0 = 0; k0 < HH; k0 += 64) {
#pragma unroll
    for (int i = 0; i < 4; ++i) {
      int idx = tid + i * 256;
      int r = idx >> 4, c4 = idx & 15;
      float4 v = *(const float4*)(x + (size_t)s_tok[r] * HH + k0 + c4 * 4);
      unsigned long long pk = (unsigned long long)f2bf(v.x)
                            | ((unsigned long long)f2bf(v.y) << 16)
                            | ((unsigned long long)f2bf(v.z) << 32)
                            | ((unsigned long long)f2bf(v.w) << 48);
      *(unsigned long long*)(&sA[r][c4 * 4]) = pk;
    }
#pragma unroll
    for (int i = 0; i < 4; ++i) {
      int idx = tid + i * 256;
      int kk = idx >> 4, c4 = idx & 15;
      float4 v = *(const float4*)(w1e + (size_t)(k0 + kk) * II + n0 + c4 * 4);
      sB[c4 * 4 + 0][kk] = f2bf(v.x);
      sB[c4 * 4 + 1][kk] = f2bf(v.y);
      sB[c4 * 4 + 2][kk] = f2bf(v.z);
      sB[c4 * 4 + 3][kk] = f2bf(v.w);
    }
    __syncthreads();
#pragma unroll
    for (int kk = 0; kk < 64; kk += 32) {
      bf16x8 af[2], bg[2];
#pragma unroll
      for (int m = 0; m < 2; ++m) af[m] = *(const bf16x8*)(&sA[wm * 32 + m * 16 + fr][kk + kg * 8]);
#pragma unroll
      for (int n = 0; n < 2; ++n) bg[n] = *(const bf16x8*)(&sB[wn * 32 + n * 16 + fr][kk + kg * 8]);
#pragma unroll
      for (int m = 0; m < 2; ++m)
#pragma unroll
        for (int n = 0; n < 2; ++n)
          acc[m][n] = __builtin_amdgcn_mfma_f32_16x16x32_bf16(af[m], bg[n], acc[m][n], 0, 0, 0);
    }
    __syncthreads();
  }
#pragma unroll
  for (int m = 0; m < 2; ++m)
#pragma unroll
    for (int n = 0; n < 2; ++n)
#pragma unroll
      for (int r = 0; r < 4; ++r) {
        int lr = wm * 32 + m * 16 + kg * 4 + r;
        int lc = wn * 32 + n * 16 + fr;
        if (row0 + lr < n_e) {
          float v = acc[m][n][r];
          float s = v / (1.f + expf(-v));
          mid[(size_t)(g_off + row0 + lr) * II + n0 + lc] = f2bf(s);
        }
      }
}

__launch_bounds__(256, 2)
__global__ void gemm2_small(const u16* __restrict__ mid, const float* __restrict__ w2,
                            const int* __restrict__ tok_list, const float* __restrict__ wt_list,
                            const int* __restrict__ offsets, float* __restrict__ out) {
  int e = blockIdx.z;
  int g_off = offsets[e];
  int n_e = offsets[e + 1] - g_off;
  int row0 = blockIdx.y * 64;
  if (row0 >= n_e) return;
  int n0 = blockIdx.x * 64;
  __shared__ u16 sA[64][72];
  __shared__ u16 sB[64][72];
  __shared__ int s_tok[64];
  __shared__ float s_wt[64];
  int tid = threadIdx.x;
  if (tid < 64) {
    int r = row0 + tid;
    int cr = (r < n_e) ? r : (n_e - 1);
    s_tok[tid] = tok_list[g_off + cr];
    s_wt[tid] = wt_list[g_off + cr];
  }
  __syncthreads();
  int lane = tid & 63;
  int wv = tid >> 6;
  int wm = wv >> 1, wn = wv & 1;
  int fr = lane & 15, kg = lane >> 4;
  f32x4 acc[2][2];
#pragma unroll
  for (int i = 0; i < 2; ++i)
#pragma unroll
    for (int j = 0; j < 2; ++j) acc[i][j] = (f32x4){0.f, 0.f, 0.f, 0.f};
  const float* w2e = w2 + (size_t)e * II * HH;
  for (int k0 = 0; k0 < II; k0 += 64) {
#pragma unroll
    for (int i = 0; i < 2; ++i) {
      int idx = tid + i * 256;
      int r = idx >> 3, c8 = idx & 7;
      int gr = row0 + r; if (gr >= n_e) gr = n_e - 1;
      uint4 v = *(const uint4*)(mid + (size_t)(g_off + gr) * II + k0 + c8 * 8);
      *(uint4*)(&sA[r][c8 * 8]) = v;
    }
#pragma unroll
    for (int i = 0; i < 4; ++i) {
      int idx = tid + i * 256;
      int kk = idx >> 4, c4 = idx & 15;
      float4 v = *(const float4*)(w2e + (size_t)(k0 + kk) * HH + n0 + c4 * 4);
      sB[c4 * 4 + 0][kk] = f2bf(v.x);
      sB[c4 * 4 + 1][kk] = f2bf(v.y);
      sB[c4 * 4 + 2][kk] = f2bf(v.z);
      sB[c4 * 4 + 3][kk] = f2bf(v.w);
    }
    __syncthreads();
#pragma unroll
    for (int kk = 0; kk < 64; kk += 32) {
      bf16x8 af[2], bg[2];
#pragma unroll
      for (int m = 0; m < 2; ++m) af[m] = *(const bf16x8*)(&sA[wm * 32 + m * 16 + fr][kk + kg * 8]);
#pragma unroll
      for (int n = 0; n < 2; ++n) bg[n] = *(const bf16x8*)(&sB[wn * 32 + n * 16 + fr][kk + kg * 8]);
#pragma unroll
      for (int m = 0; m < 2; ++m)
#pragma unroll
        for (int n = 0; n < 2; ++n)
          acc[m][n] = __builtin_amdgcn_mfma_f32_16x16x32_bf16(af[m], bg[n], acc[m][n], 0, 0, 0);
    }
    __syncthreads();
  }
#pragma unroll
  for (int m = 0; m < 2; ++m)
#pragma unroll
    for (int n = 0; n < 2; ++n)
#pragma unroll
      for (int r = 0; r < 4; ++r) {
        int lr = wm * 32 + m * 16 + kg * 4 + r;
        int lc = wn * 32 + n * 16 + fr;
        if (row0 + lr < n_e) {
          float v = acc[m][n][r] * s_wt[lr];
          atomicAdd(out + (size_t)s_tok[lr] * HH + n0 + lc, v);
        }
      }
}

extern "C" void kernel_launch(void* const* d_in, const int* in_sizes, int n_in,
                              void* d_out, int out_size, void* d_ws, size_t ws_size,
                              hipStream_t stream) {
  const float* x  = (const float*)d_in[0];
  const float* gw = (const float*)d_in[1];
  const float* w1 = (const float*)d_in[2];
  const float* w2 = (const float*)d_in[3];
  float* out = (float*)d_out;

  char* ws = (char*)d_ws;
  int*   tk_id    = (int*)(ws);
  float* tk_w     = (float*)(ws + 16384);
  int*   counts   = (int*)(ws + 32768);
  int*   cursor   = (int*)(ws + 32800);
  int*   offsets  = (int*)(ws + 32832);
  int*   tok_list = (int*)(ws + 33024);
  float* wt_list  = (float*)(ws + 49408);

  u16* xg   = (u16*)(ws + (1u << 20));          // [4224][2048] bf16
  u16* midBp = (u16*)(ws + (20u << 20));        // [4224][1408] bf16
  u16* w1b  = (u16*)(ws + (33u << 20));         // [8][1408][2048] bf16
  u16* w2b  = (u16*)(ws + 80740352u);           // [8][2048][1408] bf16
  float* midF = (float*)(ws + 126877696u);      // [4096][1408] f32
  const size_t NEED_BASE = 126877696u;
  const size_t NEED_KS   = 126877696u + (size_t)TT * 2 * II * 4;  // +23.1 MB

  bool ks_tier   = (ws_size >= NEED_KS);
  bool fast_tier = (ws_size >= NEED_BASE);

  zero_kernel<<<2048, 256, 0, stream>>>((float4*)out, TT * HH / 4,
                                        ks_tier ? (float4*)midF : nullptr,
                                        TT * 2 * II / 4, counts);
  router_kernel<<<TT, 64, 0, stream>>>(x, gw, tk_id, tk_w, counts);
  scan_kernel<<<1, 64, 0, stream>>>(counts, offsets, cursor);
  assign_kernel<<<TT / 256, 256, 0, stream>>>(tk_id, tk_w, offsets, cursor, tok_list, wt_list);

  if (fast_tier) {
    gather_x_kernel<<<2 * TT, 256, 0, stream>>>(x, tok_list, xg);
    convtrans_kernel<<<dim3(II / 64, HH / 64, EE), 256, 0, stream>>>(w1, w1b, HH, II);
    convtrans_kernel<<<dim3(HH / 64, II / 64, EE), 256, 0, stream>>>(w2, w2b, II, HH);
    if (ks_tier) {
      // K-split x2 GEMM1 -> fp32 atomics -> silu pass; K-split x2 GEMM2 -> out atomics
      moe_gemm<HH, 2, 1><<<dim3(EE, 2 * (II / 128), 16), 256, 0, stream>>>(
          xg, w1b, tok_list, wt_list, offsets, midBp, midF, out);
      silu_kernel<<<2816, 256, 0, stream>>>(midF, midBp, TT * 2 * II / 8);
      moe_gemm<II, 2, 2><<<dim3(EE, 2 * (HH / 128), 16), 256, 0, stream>>>(
          midBp, w2b, tok_list, wt_list, offsets, midBp, midF, out);
    } else {
      moe_gemm<HH, 1, 0><<<dim3(EE, II / 128, 16), 256, 0, stream>>>(
          xg, w1b, tok_list, wt_list, offsets, midBp, midF, out);
      moe_gemm<II, 1, 2><<<dim3(EE, HH / 128, 16), 256, 0, stream>>>(
          midBp, w2b, tok_list, wt_list, offsets, midBp, midF, out);
    }
  } else {
    u16* mid0 = (u16*)(ws + 131072);
    gemm1_small<<<dim3(II / 64, TT / 64, EE), 256, 0, stream>>>(x, w1, tok_list, offsets, mid0);
    gemm2_small<<<dim3(HH / 64, TT / 64, EE), 256, 0, stream>>>(mid0, w2, tok_list, wt_list, offsets, out);
  }
}

// Round 4
// 289.511 us; speedup vs baseline: 1.1048x; 1.1048x over previous
//
#include <hip/hip_runtime.h>
#include <hip/hip_bf16.h>
#include <math.h>

#define TT 2048
#define HH 2048
#define EE 8
#define II 1408

typedef short bf16x8 __attribute__((ext_vector_type(8)));
typedef float f32x4 __attribute__((ext_vector_type(4)));
typedef unsigned int u32;
typedef unsigned short u16;

__device__ __forceinline__ u16 f2bf(float f) {
  union { float f; u32 u; } v; v.f = f;
  u32 r = v.u + 0x7fffu + ((v.u >> 16) & 1u);
  return (u16)(r >> 16);
}

__device__ __forceinline__ void gload16(const void* g, void* l) {
  __builtin_amdgcn_global_load_lds((const __attribute__((address_space(1))) u32*)g,
                                   (__attribute__((address_space(3))) u32*)l, 16, 0, 0);
}

// ---------------- zero out + counters ----------------
__global__ void zero_kernel(float4* __restrict__ out4, int n4, int* __restrict__ counts) {
  int i = blockIdx.x * blockDim.x + threadIdx.x;
  int stride = gridDim.x * blockDim.x;
  float4 z; z.x = 0.f; z.y = 0.f; z.z = 0.f; z.w = 0.f;
  for (int j = i; j < n4; j += stride) out4[j] = z;
  if (blockIdx.x == 0 && threadIdx.x < 2 * EE) counts[threadIdx.x] = 0;
}

// ---------------- router ----------------
__global__ void router_kernel(const float* __restrict__ x, const float* __restrict__ gw,
                              int* __restrict__ tk_id, float* __restrict__ tk_w,
                              int* __restrict__ counts) {
  int t = blockIdx.x;
  int lane = threadIdx.x;
  float acc[EE];
#pragma unroll
  for (int e = 0; e < EE; ++e) acc[e] = 0.f;
  const float* xr = x + (size_t)t * HH;
  for (int h = lane; h < HH; h += 64) {
    float xv = xr[h];
    const float* g = gw + (size_t)h * EE;
#pragma unroll
    for (int e = 0; e < EE; ++e) acc[e] += xv * g[e];
  }
#pragma unroll
  for (int off = 32; off > 0; off >>= 1) {
#pragma unroll
    for (int e = 0; e < EE; ++e) acc[e] += __shfl_down(acc[e], off, 64);
  }
  if (lane == 0) {
    int i0 = 0;
#pragma unroll
    for (int e = 1; e < EE; ++e) if (acc[e] > acc[i0]) i0 = e;
    int i1 = (i0 == 0) ? 1 : 0;
#pragma unroll
    for (int e = 0; e < EE; ++e) { if (e == i0) continue; if (acc[e] > acc[i1]) i1 = e; }
    float d = acc[i1] - acc[i0];
    float p1 = expf(d);
    float w0 = 1.f / (1.f + p1);
    float w1v = p1 * w0;
    tk_id[2 * t] = i0; tk_id[2 * t + 1] = i1;
    tk_w[2 * t] = w0;  tk_w[2 * t + 1] = w1v;
    atomicAdd(&counts[i0], 1);
    atomicAdd(&counts[i1], 1);
  }
}

// ---------------- scan ----------------
__global__ void scan_kernel(const int* __restrict__ counts, int* __restrict__ offsets,
                            int* __restrict__ cursor) {
  if (threadIdx.x == 0) {
    int s = 0;
    for (int e = 0; e < EE; ++e) { offsets[e] = s; s += counts[e]; cursor[e] = 0; }
    offsets[EE] = s;
  }
}

// ---------------- assign ----------------
__global__ void assign_kernel(const int* __restrict__ tk_id, const float* __restrict__ tk_w,
                              const int* __restrict__ offsets, int* __restrict__ cursor,
                              int* __restrict__ tok_list, float* __restrict__ wt_list) {
  int t = blockIdx.x * blockDim.x + threadIdx.x;
  if (t >= TT) return;
#pragma unroll
  for (int k = 0; k < 2; ++k) {
    int e = tk_id[2 * t + k];
    int p = atomicAdd(&cursor[e], 1);
    int slot = offsets[e] + p;
    tok_list[slot] = t;
    wt_list[slot] = tk_w[2 * t + k];
  }
}

// ---------------- gather x -> bf16 xg[slot][H] ----------------
__global__ void gather_x_kernel(const float* __restrict__ x, const int* __restrict__ tok_list,
                                u16* __restrict__ xg) {
  int slot = blockIdx.x;
  int tok = tok_list[slot];
  int c = threadIdx.x * 8;
  float4 v0 = *(const float4*)(x + (size_t)tok * HH + c);
  float4 v1 = *(const float4*)(x + (size_t)tok * HH + c + 4);
  u16 o[8] = { f2bf(v0.x), f2bf(v0.y), f2bf(v0.z), f2bf(v0.w),
               f2bf(v1.x), f2bf(v1.y), f2bf(v1.z), f2bf(v1.w) };
  *(uint4*)(xg + (size_t)slot * HH + c) = *(uint4*)o;
}

// ---------------- convert + transpose: w[e][K][N] fp32 -> wb[e][N][K] bf16 ----------------
__global__ void convtrans_kernel(const float* __restrict__ w, u16* __restrict__ wb,
                                 int K, int N) {
  int e = blockIdx.z;
  int n0 = blockIdx.x * 64, k0 = blockIdx.y * 64;
  __shared__ u16 sT[64][72];
  const float* we = w + (size_t)e * K * N;
  u16* wbe = wb + (size_t)e * K * N;
  int tid = threadIdx.x;
  int kl = tid >> 4, n4 = tid & 15;
#pragma unroll
  for (int j = 0; j < 4; ++j) {
    int k = kl + j * 16;
    float4 v = *(const float4*)(we + (size_t)(k0 + k) * N + n0 + n4 * 4);
    sT[n4 * 4 + 0][k] = f2bf(v.x);
    sT[n4 * 4 + 1][k] = f2bf(v.y);
    sT[n4 * 4 + 2][k] = f2bf(v.z);
    sT[n4 * 4 + 3][k] = f2bf(v.w);
  }
  __syncthreads();
  int nl = tid >> 3, kc = tid & 7;
#pragma unroll
  for (int j = 0; j < 2; ++j) {
    int n = nl + j * 32;
    uint4 v = *(const uint4*)(&sT[n][kc * 8]);
    *(uint4*)(wbe + (size_t)(n0 + n) * K + k0 + kc * 8) = v;
  }
}

// ---------------- grouped GEMM, 128x128x64, counted-vmcnt 2-deep pipeline ----------------
// A: [slot][KDIM] bf16; B: [e][Ndim][KDIM] bf16 (N-major).
// MODE 0: silu -> midB (KS must be 1).  MODE 2: atomicAdd wt-scaled into out.
template <int KDIM, int KS, int MODE>
__launch_bounds__(256)
__global__ void moe_gemm(const u16* __restrict__ A, const u16* __restrict__ B,
                         const int* __restrict__ tok_list, const float* __restrict__ wt_list,
                         const int* __restrict__ offsets,
                         u16* __restrict__ midB, float* __restrict__ out) {
  constexpr int Ndim = (MODE == 2) ? HH : II;
  constexpr int NCB = Ndim / 128;
  constexpr int KLEN = KDIM / KS;
  constexpr int NT = KLEN / 64;
  static_assert(NT >= 2, "pipeline needs >=2 K-tiles");

  int e = blockIdx.x;                 // expert = fastest dim -> XCD ~ e (L2 locality)
  int g_off = offsets[e];
  int n_e = offsets[e + 1] - g_off;
  int row0 = blockIdx.z * 128;
  if (row0 >= n_e) return;
  int cb = blockIdx.y % NCB;
  int ks = blockIdx.y / NCB;
  int n0 = cb * 128;
  int k_beg = ks * KLEN;

  __shared__ u16 sA[2][128][64];
  __shared__ u16 sB[2][128][64];
  __shared__ int s_tok[128];
  __shared__ float s_wt[128];

  int tid = threadIdx.x;
  int lane = tid & 63, wv = tid >> 6;
  int wm = wv >> 1, wn = wv & 1;
  int fr = lane & 15, kg = lane >> 4;

  if constexpr (MODE == 2) {
    if (tid < 128) {
      int r = row0 + tid;
      int cr = r < n_e ? r : n_e - 1;
      s_tok[tid] = tok_list[g_off + cr];
      s_wt[tid] = wt_list[g_off + cr];
    }
  }
  // Full barrier BEFORE any async loads: drains the s_tok/s_wt ds_writes so the
  // in-loop raw s_barriers never need lgkm coverage for them. No vmem in flight yet.
  __syncthreads();

  // staging: lane l writes 16B at LDS chunk base + l*16; chunk c = j*4 + wv = 8 rows.
  // global source col pre-swizzled (XOR involution) to match swizzled ds_read.
  int rA = lane >> 3;
  int colsw = ((lane & 7) ^ rA) * 8;
  const u16* Abase = A + (size_t)(g_off + row0 + rA) * KDIM + k_beg + colsw;
  const u16* Bbase = B + (size_t)e * (size_t)Ndim * KDIM + (size_t)(n0 + rA) * KDIM + k_beg + colsw;

  f32x4 acc[4][4];
#pragma unroll
  for (int m = 0; m < 4; ++m)
#pragma unroll
    for (int n = 0; n < 4; ++n)
      acc[m][n] = (f32x4){0.f, 0.f, 0.f, 0.f};

  auto stage = [&](int buf, int kof) {
#pragma unroll
    for (int j = 0; j < 4; ++j) {
      int c = j * 4 + wv;
      gload16(Abase + (size_t)c * 8 * KDIM + kof, &sA[buf][c * 8][0]);
      gload16(Bbase + (size_t)c * 8 * KDIM + kof, &sB[buf][c * 8][0]);
    }
  };

  // prologue: 2-deep prefetch (8 loads per wave per tile)
  stage(0, 0);
  stage(1, 64);

  for (int t = 0; t < NT; ++t) {
    int cur = t & 1;
    // counted wait: leave tile t+1's 8 loads in flight (T4); drain only at the end
    if (t + 1 < NT) { asm volatile("s_waitcnt vmcnt(8)" ::: "memory"); }
    else            { asm volatile("s_waitcnt vmcnt(0)" ::: "memory"); }
    __builtin_amdgcn_s_barrier();          // all waves' tile-t loads landed
    __builtin_amdgcn_sched_barrier(0);
#pragma unroll
    for (int kh = 0; kh < 2; ++kh) {
      bf16x8 af[4], bg[4];
      int cbyte = (kh * 64 + kg * 16) ^ ((fr & 7) << 4);
#pragma unroll
      for (int m = 0; m < 4; ++m)
        af[m] = *(const bf16x8*)((const char*)&sA[cur][0][0] + (wm * 64 + m * 16 + fr) * 128 + cbyte);
#pragma unroll
      for (int n = 0; n < 4; ++n)
        bg[n] = *(const bf16x8*)((const char*)&sB[cur][0][0] + (wn * 64 + n * 16 + fr) * 128 + cbyte);
      __builtin_amdgcn_s_setprio(1);
#pragma unroll
      for (int m = 0; m < 4; ++m)
#pragma unroll
        for (int n = 0; n < 4; ++n)
          acc[m][n] = __builtin_amdgcn_mfma_f32_16x16x32_bf16(af[m], bg[n], acc[m][n], 0, 0, 0);
      __builtin_amdgcn_s_setprio(0);
    }
    __builtin_amdgcn_s_barrier();          // all waves done reading buf[cur]
    if (t + 2 < NT) stage(cur, (t + 2) * 64);
  }

#pragma unroll
  for (int m = 0; m < 4; ++m) {
    int lr = wm * 64 + m * 16 + kg * 4;
#pragma unroll
    for (int n = 0; n < 4; ++n) {
      int lc = wn * 64 + n * 16 + fr;
#pragma unroll
      for (int r = 0; r < 4; ++r) {
        int rr = lr + r;
        if (row0 + rr < n_e) {
          if constexpr (MODE == 0) {
            float v = acc[m][n][r];
            float s = v / (1.f + expf(-v));
            midB[(size_t)(g_off + row0 + rr) * II + n0 + lc] = f2bf(s);
          } else {
            float v = acc[m][n][r] * s_wt[rr];
            atomicAdd(out + (size_t)s_tok[rr] * HH + n0 + lc, v);
          }
        }
      }
    }
  }
}

// ================= small fallback (round-1, proven; used only if ws too small) ===========
__launch_bounds__(256, 2)
__global__ void gemm1_small(const float* __restrict__ x, const float* __restrict__ w1,
                            const int* __restrict__ tok_list, const int* __restrict__ offsets,
                            u16* __restrict__ mid) {
  int e = blockIdx.z;
  int g_off = offsets[e];
  int n_e = offsets[e + 1] - g_off;
  int row0 = blockIdx.y * 64;
  if (row0 >= n_e) return;
  int n0 = blockIdx.x * 64;
  __shared__ u16 sA[64][72];
  __shared__ u16 sB[64][72];
  __shared__ int s_tok[64];
  int tid = threadIdx.x;
  if (tid < 64) {
    int r = row0 + tid;
    s_tok[tid] = tok_list[g_off + ((r < n_e) ? r : (n_e - 1))];
  }
  __syncthreads();
  int lane = tid & 63;
  int wv = tid >> 6;
  int wm = wv >> 1, wn = wv & 1;
  int fr = lane & 15, kg = lane >> 4;
  f32x4 acc[2][2];
#pragma unroll
  for (int i = 0; i < 2; ++i)
#pragma unroll
    for (int j = 0; j < 2; ++j) acc[i][j] = (f32x4){0.f, 0.f, 0.f, 0.f};
  const float* w1e = w1 + (size_t)e * HH * II;
  for (int k0 = 0; k0 < HH; k0 += 64) {
#pragma unroll
    for (int i = 0; i < 4; ++i) {
      int idx = tid + i * 256;
      int r = idx >> 4, c4 = idx & 15;
      float4 v = *(const float4*)(x + (size_t)s_tok[r] * HH + k0 + c4 * 4);
      unsigned long long pk = (unsigned long long)f2bf(v.x)
                            | ((unsigned long long)f2bf(v.y) << 16)
                            | ((unsigned long long)f2bf(v.z) << 32)
                            | ((unsigned long long)f2bf(v.w) << 48);
      *(unsigned long long*)(&sA[r][c4 * 4]) = pk;
    }
#pragma unroll
    for (int i = 0; i < 4; ++i) {
      int idx = tid + i * 256;
      int kk = idx >> 4, c4 = idx & 15;
      float4 v = *(const float4*)(w1e + (size_t)(k0 + kk) * II + n0 + c4 * 4);
      sB[c4 * 4 + 0][kk] = f2bf(v.x);
      sB[c4 * 4 + 1][kk] = f2bf(v.y);
      sB[c4 * 4 + 2][kk] = f2bf(v.z);
      sB[c4 * 4 + 3][kk] = f2bf(v.w);
    }
    __syncthreads();
#pragma unroll
    for (int kk = 0; kk < 64; kk += 32) {
      bf16x8 af[2], bg[2];
#pragma unroll
      for (int m = 0; m < 2; ++m) af[m] = *(const bf16x8*)(&sA[wm * 32 + m * 16 + fr][kk + kg * 8]);
#pragma unroll
      for (int n = 0; n < 2; ++n) bg[n] = *(const bf16x8*)(&sB[wn * 32 + n * 16 + fr][kk + kg * 8]);
#pragma unroll
      for (int m = 0; m < 2; ++m)
#pragma unroll
        for (int n = 0; n < 2; ++n)
          acc[m][n] = __builtin_amdgcn_mfma_f32_16x16x32_bf16(af[m], bg[n], acc[m][n], 0, 0, 0);
    }
    __syncthreads();
  }
#pragma unroll
  for (int m = 0; m < 2; ++m)
#pragma unroll
    for (int n = 0; n < 2; ++n)
#pragma unroll
      for (int r = 0; r < 4; ++r) {
        int lr = wm * 32 + m * 16 + kg * 4 + r;
        int lc = wn * 32 + n * 16 + fr;
        if (row0 + lr < n_e) {
          float v = acc[m][n][r];
          float s = v / (1.f + expf(-v));
          mid[(size_t)(g_off + row0 + lr) * II + n0 + lc] = f2bf(s);
        }
      }
}

__launch_bounds__(256, 2)
__global__ void gemm2_small(const u16* __restrict__ mid, const float* __restrict__ w2,
                            const int* __restrict__ tok_list, const float* __restrict__ wt_list,
                            const int* __restrict__ offsets, float* __restrict__ out) {
  int e = blockIdx.z;
  int g_off = offsets[e];
  int n_e = offsets[e + 1] - g_off;
  int row0 = blockIdx.y * 64;
  if (row0 >= n_e) return;
  int n0 = blockIdx.x * 64;
  __shared__ u16 sA[64][72];
  __shared__ u16 sB[64][72];
  __shared__ int s_tok[64];
  __shared__ float s_wt[64];
  int tid = threadIdx.x;
  if (tid < 64) {
    int r = row0 + tid;
    int cr = (r < n_e) ? r : (n_e - 1);
    s_tok[tid] = tok_list[g_off + cr];
    s_wt[tid] = wt_list[g_off + cr];
  }
  __syncthreads();
  int lane = tid & 63;
  int wv = tid >> 6;
  int wm = wv >> 1, wn = wv & 1;
  int fr = lane & 15, kg = lane >> 4;
  f32x4 acc[2][2];
#pragma unroll
  for (int i = 0; i < 2; ++i)
#pragma unroll
    for (int j = 0; j < 2; ++j) acc[i][j] = (f32x4){0.f, 0.f, 0.f, 0.f};
  const float* w2e = w2 + (size_t)e * II * HH;
  for (int k0 = 0; k0 < II; k0 += 64) {
#pragma unroll
    for (int i = 0; i < 2; ++i) {
      int idx = tid + i * 256;
      int r = idx >> 3, c8 = idx & 7;
      int gr = row0 + r; if (gr >= n_e) gr = n_e - 1;
      uint4 v = *(const uint4*)(mid + (size_t)(g_off + gr) * II + k0 + c8 * 8);
      *(uint4*)(&sA[r][c8 * 8]) = v;
    }
#pragma unroll
    for (int i = 0; i < 4; ++i) {
      int idx = tid + i * 256;
      int kk = idx >> 4, c4 = idx & 15;
      float4 v = *(const float4*)(w2e + (size_t)(k0 + kk) * HH + n0 + c4 * 4);
      sB[c4 * 4 + 0][kk] = f2bf(v.x);
      sB[c4 * 4 + 1][kk] = f2bf(v.y);
      sB[c4 * 4 + 2][kk] = f2bf(v.z);
      sB[c4 * 4 + 3][kk] = f2bf(v.w);
    }
    __syncthreads();
#pragma unroll
    for (int kk = 0; kk < 64; kk += 32) {
      bf16x8 af[2], bg[2];
#pragma unroll
      for (int m = 0; m < 2; ++m) af[m] = *(const bf16x8*)(&sA[wm * 32 + m * 16 + fr][kk + kg * 8]);
#pragma unroll
      for (int n = 0; n < 2; ++n) bg[n] = *(const bf16x8*)(&sB[wn * 32 + n * 16 + fr][kk + kg * 8]);
#pragma unroll
      for (int m = 0; m < 2; ++m)
#pragma unroll
        for (int n = 0; n < 2; ++n)
          acc[m][n] = __builtin_amdgcn_mfma_f32_16x16x32_bf16(af[m], bg[n], acc[m][n], 0, 0, 0);
    }
    __syncthreads();
  }
#pragma unroll
  for (int m = 0; m < 2; ++m)
#pragma unroll
    for (int n = 0; n < 2; ++n)
#pragma unroll
      for (int r = 0; r < 4; ++r) {
        int lr = wm * 32 + m * 16 + kg * 4 + r;
        int lc = wn * 32 + n * 16 + fr;
        if (row0 + lr < n_e) {
          float v = acc[m][n][r] * s_wt[lr];
          atomicAdd(out + (size_t)s_tok[lr] * HH + n0 + lc, v);
        }
      }
}

extern "C" void kernel_launch(void* const* d_in, const int* in_sizes, int n_in,
                              void* d_out, int out_size, void* d_ws, size_t ws_size,
                              hipStream_t stream) {
  const float* x  = (const float*)d_in[0];
  const float* gw = (const float*)d_in[1];
  const float* w1 = (const float*)d_in[2];
  const float* w2 = (const float*)d_in[3];
  float* out = (float*)d_out;

  char* ws = (char*)d_ws;
  int*   tk_id    = (int*)(ws);
  float* tk_w     = (float*)(ws + 16384);
  int*   counts   = (int*)(ws + 32768);
  int*   cursor   = (int*)(ws + 32800);
  int*   offsets  = (int*)(ws + 32832);
  int*   tok_list = (int*)(ws + 33024);
  float* wt_list  = (float*)(ws + 49408);

  u16* xg    = (u16*)(ws + (1u << 20));   // [4224][2048] bf16
  u16* midBp = (u16*)(ws + (20u << 20));  // [4224][1408] bf16
  u16* w1b   = (u16*)(ws + (33u << 20));  // [8][1408][2048] bf16 (N-major)
  u16* w2b   = (u16*)(ws + 80740352u);    // [8][2048][1408] bf16 (N-major)
  const size_t NEED = 126877696u;

  zero_kernel<<<1024, 256, 0, stream>>>((float4*)out, TT * HH / 4, counts);
  router_kernel<<<TT, 64, 0, stream>>>(x, gw, tk_id, tk_w, counts);
  scan_kernel<<<1, 64, 0, stream>>>(counts, offsets, cursor);
  assign_kernel<<<TT / 256, 256, 0, stream>>>(tk_id, tk_w, offsets, cursor, tok_list, wt_list);

  if (ws_size >= NEED) {
    gather_x_kernel<<<2 * TT, 256, 0, stream>>>(x, tok_list, xg);
    convtrans_kernel<<<dim3(II / 64, HH / 64, EE), 256, 0, stream>>>(w1, w1b, HH, II);
    convtrans_kernel<<<dim3(HH / 64, II / 64, EE), 256, 0, stream>>>(w2, w2b, II, HH);
    // gemm1: no K-split (352 real blocks) -> direct silu->bf16
    moe_gemm<HH, 1, 0><<<dim3(EE, II / 128, 16), 256, 0, stream>>>(
        xg, w1b, tok_list, wt_list, offsets, midBp, out);
    // gemm2: K-split x2 (1024 real blocks), atomic epilogue
    moe_gemm<II, 2, 2><<<dim3(EE, 2 * (HH / 128), 16), 256, 0, stream>>>(
        midBp, w2b, tok_list, wt_list, offsets, midBp, out);
  } else {
    u16* mid0 = (u16*)(ws + 131072);
    gemm1_small<<<dim3(II / 64, TT / 64, EE), 256, 0, stream>>>(x, w1, tok_list, offsets, mid0);
    gemm2_small<<<dim3(HH / 64, TT / 64, EE), 256, 0, stream>>>(mid0, w2, tok_list, wt_list, offsets, out);
  }
}

// Round 5
// 285.149 us; speedup vs baseline: 1.1217x; 1.0153x over previous
//
#include <hip/hip_runtime.h>
#include <hip/hip_bf16.h>
#include <math.h>

#define TT 2048
#define HH 2048
#define EE 8
#define II 1408

typedef short bf16x8 __attribute__((ext_vector_type(8)));
typedef float f32x4 __attribute__((ext_vector_type(4)));
typedef unsigned int u32;
typedef unsigned short u16;

__device__ __forceinline__ u16 f2bf(float f) {
  union { float f; u32 u; } v; v.f = f;
  u32 r = v.u + 0x7fffu + ((v.u >> 16) & 1u);
  return (u16)(r >> 16);
}

__device__ __forceinline__ void gload16(const void* g, void* l) {
  __builtin_amdgcn_global_load_lds((const __attribute__((address_space(1))) u32*)g,
                                   (__attribute__((address_space(3))) u32*)l, 16, 0, 0);
}

// ---------------- zero out + counters ----------------
__global__ void zero_kernel(float4* __restrict__ out4, int n4, int* __restrict__ counts) {
  int i = blockIdx.x * blockDim.x + threadIdx.x;
  int stride = gridDim.x * blockDim.x;
  float4 z; z.x = 0.f; z.y = 0.f; z.z = 0.f; z.w = 0.f;
  for (int j = i; j < n4; j += stride) out4[j] = z;
  if (blockIdx.x == 0 && threadIdx.x < 2 * EE) counts[threadIdx.x] = 0;
}

// ---------------- router ----------------
__global__ void router_kernel(const float* __restrict__ x, const float* __restrict__ gw,
                              int* __restrict__ tk_id, float* __restrict__ tk_w,
                              int* __restrict__ counts) {
  int t = blockIdx.x;
  int lane = threadIdx.x;
  float acc[EE];
#pragma unroll
  for (int e = 0; e < EE; ++e) acc[e] = 0.f;
  const float* xr = x + (size_t)t * HH;
  for (int h = lane; h < HH; h += 64) {
    float xv = xr[h];
    const float* g = gw + (size_t)h * EE;
#pragma unroll
    for (int e = 0; e < EE; ++e) acc[e] += xv * g[e];
  }
#pragma unroll
  for (int off = 32; off > 0; off >>= 1) {
#pragma unroll
    for (int e = 0; e < EE; ++e) acc[e] += __shfl_down(acc[e], off, 64);
  }
  if (lane == 0) {
    int i0 = 0;
#pragma unroll
    for (int e = 1; e < EE; ++e) if (acc[e] > acc[i0]) i0 = e;
    int i1 = (i0 == 0) ? 1 : 0;
#pragma unroll
    for (int e = 0; e < EE; ++e) { if (e == i0) continue; if (acc[e] > acc[i1]) i1 = e; }
    float d = acc[i1] - acc[i0];
    float p1 = expf(d);
    float w0 = 1.f / (1.f + p1);
    float w1v = p1 * w0;
    tk_id[2 * t] = i0; tk_id[2 * t + 1] = i1;
    tk_w[2 * t] = w0;  tk_w[2 * t + 1] = w1v;
    atomicAdd(&counts[i0], 1);
    atomicAdd(&counts[i1], 1);
  }
}

// ---------------- scan ----------------
__global__ void scan_kernel(const int* __restrict__ counts, int* __restrict__ offsets,
                            int* __restrict__ cursor) {
  if (threadIdx.x == 0) {
    int s = 0;
    for (int e = 0; e < EE; ++e) { offsets[e] = s; s += counts[e]; cursor[e] = 0; }
    offsets[EE] = s;
  }
}

// ---------------- assign ----------------
__global__ void assign_kernel(const int* __restrict__ tk_id, const float* __restrict__ tk_w,
                              const int* __restrict__ offsets, int* __restrict__ cursor,
                              int* __restrict__ tok_list, float* __restrict__ wt_list) {
  int t = blockIdx.x * blockDim.x + threadIdx.x;
  if (t >= TT) return;
#pragma unroll
  for (int k = 0; k < 2; ++k) {
    int e = tk_id[2 * t + k];
    int p = atomicAdd(&cursor[e], 1);
    int slot = offsets[e] + p;
    tok_list[slot] = t;
    wt_list[slot] = tk_w[2 * t + k];
  }
}

// ---------------- gather x -> bf16 xg[slot][H] ----------------
__global__ void gather_x_kernel(const float* __restrict__ x, const int* __restrict__ tok_list,
                                u16* __restrict__ xg) {
  int slot = blockIdx.x;
  int tok = tok_list[slot];
  int c = threadIdx.x * 8;
  float4 v0 = *(const float4*)(x + (size_t)tok * HH + c);
  float4 v1 = *(const float4*)(x + (size_t)tok * HH + c + 4);
  u16 o[8] = { f2bf(v0.x), f2bf(v0.y), f2bf(v0.z), f2bf(v0.w),
               f2bf(v1.x), f2bf(v1.y), f2bf(v1.z), f2bf(v1.w) };
  *(uint4*)(xg + (size_t)slot * HH + c) = *(uint4*)o;
}

// ---------------- convert + transpose: w[e][K][N] fp32 -> wb[e][N][K] bf16 ----------------
__global__ void convtrans_kernel(const float* __restrict__ w, u16* __restrict__ wb,
                                 int K, int N) {
  int e = blockIdx.z;
  int n0 = blockIdx.x * 64, k0 = blockIdx.y * 64;
  __shared__ u16 sT[64][72];
  const float* we = w + (size_t)e * K * N;
  u16* wbe = wb + (size_t)e * K * N;
  int tid = threadIdx.x;
  int kl = tid >> 4, n4 = tid & 15;
#pragma unroll
  for (int j = 0; j < 4; ++j) {
    int k = kl + j * 16;
    float4 v = *(const float4*)(we + (size_t)(k0 + k) * N + n0 + n4 * 4);
    sT[n4 * 4 + 0][k] = f2bf(v.x);
    sT[n4 * 4 + 1][k] = f2bf(v.y);
    sT[n4 * 4 + 2][k] = f2bf(v.z);
    sT[n4 * 4 + 3][k] = f2bf(v.w);
  }
  __syncthreads();
  int nl = tid >> 3, kc = tid & 7;
#pragma unroll
  for (int j = 0; j < 2; ++j) {
    int n = nl + j * 32;
    uint4 v = *(const uint4*)(&sT[n][kc * 8]);
    *(uint4*)(wbe + (size_t)(n0 + n) * K + k0 + kc * 8) = v;
  }
}

// ---------------- grouped GEMM, BM=128 x BN x 64, single-buffer m97-style loop ----------------
// A: [slot][KDIM] bf16; B: [e][Ndim][KDIM] bf16 (N-major).
// MODE 0: silu -> midB (KS must be 1).  MODE 2: atomicAdd wt-scaled into out.
// High occupancy (small LDS, 4-5 blocks/CU) provides TLP latency hiding; plain barriers.
template <int BN, int KDIM, int KS, int MODE>
__launch_bounds__(256)
__global__ void moe_gemm(const u16* __restrict__ A, const u16* __restrict__ B,
                         const int* __restrict__ tok_list, const float* __restrict__ wt_list,
                         const int* __restrict__ offsets,
                         u16* __restrict__ midB, float* __restrict__ out) {
  constexpr int Ndim = (MODE == 2) ? HH : II;
  constexpr int NCB = Ndim / BN;
  constexpr int KLEN = KDIM / KS;
  constexpr int NT = KLEN / 64;
  constexpr int NF = BN / 32;          // N-frags per wave (2 waves span BN)

  int e = blockIdx.x;                  // expert-major grid
  int g_off = offsets[e];
  int n_e = offsets[e + 1] - g_off;
  int row0 = blockIdx.z * 128;
  if (row0 >= n_e) return;
  int cb = blockIdx.y % NCB;
  int ks = blockIdx.y / NCB;
  int n0 = cb * BN;
  int k_beg = ks * KLEN;

  __shared__ u16 sA[128][64];
  __shared__ u16 sB[BN][64];
  __shared__ int s_tok[128];
  __shared__ float s_wt[128];

  int tid = threadIdx.x;
  int lane = tid & 63, wv = tid >> 6;
  int wm = wv >> 1, wn = wv & 1;
  int fr = lane & 15, kg = lane >> 4;

  if constexpr (MODE == 2) {
    if (tid < 128) {
      int r = row0 + tid;
      int cr = r < n_e ? r : n_e - 1;
      s_tok[tid] = tok_list[g_off + cr];
      s_wt[tid] = wt_list[g_off + cr];
    }
  }

  // staging: lane l writes 16B at chunk base + l*16; chunk = 8 rows of 64 cols.
  // global source col pre-swizzled (XOR involution) to match swizzled ds_read.
  int rA = lane >> 3;
  int colsw = ((lane & 7) ^ rA) * 8;
  const u16* Abase = A + (size_t)(g_off + row0 + rA) * KDIM + k_beg + colsw;
  const u16* Bbase = B + (size_t)e * (size_t)Ndim * KDIM + (size_t)(n0 + rA) * KDIM + k_beg + colsw;

  f32x4 acc[4][NF];
#pragma unroll
  for (int m = 0; m < 4; ++m)
#pragma unroll
    for (int n = 0; n < NF; ++n)
      acc[m][n] = (f32x4){0.f, 0.f, 0.f, 0.f};

  for (int t = 0; t < NT; ++t) {
    int kof = t * 64;
    // stage A: 16 chunks, 4 per wave
#pragma unroll
    for (int j = 0; j < 4; ++j) {
      int c = wv * 4 + j;
      gload16(Abase + (size_t)c * 8 * KDIM + kof, &sA[c * 8][0]);
    }
    // stage B: BN/8 chunks, BN/32 per wave
#pragma unroll
    for (int j = 0; j < BN / 32; ++j) {
      int c = wv * (BN / 32) + j;
      gload16(Bbase + (size_t)c * 8 * KDIM + kof, &sB[c * 8][0]);
    }
    __syncthreads();   // compiler drains vmcnt before barrier; loads landed
#pragma unroll
    for (int kh = 0; kh < 2; ++kh) {
      bf16x8 af[4], bg[NF];
      int cbyte = (kh * 64 + kg * 16) ^ ((fr & 7) << 4);
#pragma unroll
      for (int m = 0; m < 4; ++m)
        af[m] = *(const bf16x8*)((const char*)&sA[0][0] + (wm * 64 + m * 16 + fr) * 128 + cbyte);
#pragma unroll
      for (int n = 0; n < NF; ++n)
        bg[n] = *(const bf16x8*)((const char*)&sB[0][0] + (wn * (BN / 2) + n * 16 + fr) * 128 + cbyte);
#pragma unroll
      for (int m = 0; m < 4; ++m)
#pragma unroll
        for (int n = 0; n < NF; ++n)
          acc[m][n] = __builtin_amdgcn_mfma_f32_16x16x32_bf16(af[m], bg[n], acc[m][n], 0, 0, 0);
    }
    __syncthreads();   // all waves done reading; safe to restage
  }

#pragma unroll
  for (int m = 0; m < 4; ++m) {
    int lr = wm * 64 + m * 16 + kg * 4;
#pragma unroll
    for (int n = 0; n < NF; ++n) {
      int lc = wn * (BN / 2) + n * 16 + fr;
#pragma unroll
      for (int r = 0; r < 4; ++r) {
        int rr = lr + r;
        if (row0 + rr < n_e) {
          if constexpr (MODE == 0) {
            float v = acc[m][n][r];
            float s = v / (1.f + expf(-v));
            midB[(size_t)(g_off + row0 + rr) * II + n0 + lc] = f2bf(s);
          } else {
            float v = acc[m][n][r] * s_wt[rr];
            atomicAdd(out + (size_t)s_tok[rr] * HH + n0 + lc, v);
          }
        }
      }
    }
  }
}

// ================= small fallback (round-1, proven; used only if ws too small) ===========
__launch_bounds__(256, 2)
__global__ void gemm1_small(const float* __restrict__ x, const float* __restrict__ w1,
                            const int* __restrict__ tok_list, const int* __restrict__ offsets,
                            u16* __restrict__ mid) {
  int e = blockIdx.z;
  int g_off = offsets[e];
  int n_e = offsets[e + 1] - g_off;
  int row0 = blockIdx.y * 64;
  if (row0 >= n_e) return;
  int n0 = blockIdx.x * 64;
  __shared__ u16 sA[64][72];
  __shared__ u16 sB[64][72];
  __shared__ int s_tok[64];
  int tid = threadIdx.x;
  if (tid < 64) {
    int r = row0 + tid;
    s_tok[tid] = tok_list[g_off + ((r < n_e) ? r : (n_e - 1))];
  }
  __syncthreads();
  int lane = tid & 63;
  int wv = tid >> 6;
  int wm = wv >> 1, wn = wv & 1;
  int fr = lane & 15, kg = lane >> 4;
  f32x4 acc[2][2];
#pragma unroll
  for (int i = 0; i < 2; ++i)
#pragma unroll
    for (int j = 0; j < 2; ++j) acc[i][j] = (f32x4){0.f, 0.f, 0.f, 0.f};
  const float* w1e = w1 + (size_t)e * HH * II;
  for (int k0 = 0; k0 < HH; k0 += 64) {
#pragma unroll
    for (int i = 0; i < 4; ++i) {
      int idx = tid + i * 256;
      int r = idx >> 4, c4 = idx & 15;
      float4 v = *(const float4*)(x + (size_t)s_tok[r] * HH + k0 + c4 * 4);
      unsigned long long pk = (unsigned long long)f2bf(v.x)
                            | ((unsigned long long)f2bf(v.y) << 16)
                            | ((unsigned long long)f2bf(v.z) << 32)
                            | ((unsigned long long)f2bf(v.w) << 48);
      *(unsigned long long*)(&sA[r][c4 * 4]) = pk;
    }
#pragma unroll
    for (int i = 0; i < 4; ++i) {
      int idx = tid + i * 256;
      int kk = idx >> 4, c4 = idx & 15;
      float4 v = *(const float4*)(w1e + (size_t)(k0 + kk) * II + n0 + c4 * 4);
      sB[c4 * 4 + 0][kk] = f2bf(v.x);
      sB[c4 * 4 + 1][kk] = f2bf(v.y);
      sB[c4 * 4 + 2][kk] = f2bf(v.z);
      sB[c4 * 4 + 3][kk] = f2bf(v.w);
    }
    __syncthreads();
#pragma unroll
    for (int kk = 0; kk < 64; kk += 32) {
      bf16x8 af[2], bg[2];
#pragma unroll
      for (int m = 0; m < 2; ++m) af[m] = *(const bf16x8*)(&sA[wm * 32 + m * 16 + fr][kk + kg * 8]);
#pragma unroll
      for (int n = 0; n < 2; ++n) bg[n] = *(const bf16x8*)(&sB[wn * 32 + n * 16 + fr][kk + kg * 8]);
#pragma unroll
      for (int m = 0; m < 2; ++m)
#pragma unroll
        for (int n = 0; n < 2; ++n)
          acc[m][n] = __builtin_amdgcn_mfma_f32_16x16x32_bf16(af[m], bg[n], acc[m][n], 0, 0, 0);
    }
    __syncthreads();
  }
#pragma unroll
  for (int m = 0; m < 2; ++m)
#pragma unroll
    for (int n = 0; n < 2; ++n)
#pragma unroll
      for (int r = 0; r < 4; ++r) {
        int lr = wm * 32 + m * 16 + kg * 4 + r;
        int lc = wn * 32 + n * 16 + fr;
        if (row0 + lr < n_e) {
          float v = acc[m][n][r];
          float s = v / (1.f + expf(-v));
          mid[(size_t)(g_off + row0 + lr) * II + n0 + lc] = f2bf(s);
        }
      }
}

__launch_bounds__(256, 2)
__global__ void gemm2_small(const u16* __restrict__ mid, const float* __restrict__ w2,
                            const int* __restrict__ tok_list, const float* __restrict__ wt_list,
                            const int* __restrict__ offsets, float* __restrict__ out) {
  int e = blockIdx.z;
  int g_off = offsets[e];
  int n_e = offsets[e + 1] - g_off;
  int row0 = blockIdx.y * 64;
  if (row0 >= n_e) return;
  int n0 = blockIdx.x * 64;
  __shared__ u16 sA[64][72];
  __shared__ u16 sB[64][72];
  __shared__ int s_tok[64];
  __shared__ float s_wt[64];
  int tid = threadIdx.x;
  if (tid < 64) {
    int r = row0 + tid;
    int cr = (r < n_e) ? r : (n_e - 1);
    s_tok[tid] = tok_list[g_off + cr];
    s_wt[tid] = wt_list[g_off + cr];
  }
  __syncthreads();
  int lane = tid & 63;
  int wv = tid >> 6;
  int wm = wv >> 1, wn = wv & 1;
  int fr = lane & 15, kg = lane >> 4;
  f32x4 acc[2][2];
#pragma unroll
  for (int i = 0; i < 2; ++i)
#pragma unroll
    for (int j = 0; j < 2; ++j) acc[i][j] = (f32x4){0.f, 0.f, 0.f, 0.f};
  const float* w2e = w2 + (size_t)e * II * HH;
  for (int k0 = 0; k0 < II; k0 += 64) {
#pragma unroll
    for (int i = 0; i < 2; ++i) {
      int idx = tid + i * 256;
      int r = idx >> 3, c8 = idx & 7;
      int gr = row0 + r; if (gr >= n_e) gr = n_e - 1;
      uint4 v = *(const uint4*)(mid + (size_t)(g_off + gr) * II + k0 + c8 * 8);
      *(uint4*)(&sA[r][c8 * 8]) = v;
    }
#pragma unroll
    for (int i = 0; i < 4; ++i) {
      int idx = tid + i * 256;
      int kk = idx >> 4, c4 = idx & 15;
      float4 v = *(const float4*)(w2e + (size_t)(k0 + kk) * HH + n0 + c4 * 4);
      sB[c4 * 4 + 0][kk] = f2bf(v.x);
      sB[c4 * 4 + 1][kk] = f2bf(v.y);
      sB[c4 * 4 + 2][kk] = f2bf(v.z);
      sB[c4 * 4 + 3][kk] = f2bf(v.w);
    }
    __syncthreads();
#pragma unroll
    for (int kk = 0; kk < 64; kk += 32) {
      bf16x8 af[2], bg[2];
#pragma unroll
      for (int m = 0; m < 2; ++m) af[m] = *(const bf16x8*)(&sA[wm * 32 + m * 16 + fr][kk + kg * 8]);
#pragma unroll
      for (int n = 0; n < 2; ++n) bg[n] = *(const bf16x8*)(&sB[wn * 32 + n * 16 + fr][kk + kg * 8]);
#pragma unroll
      for (int m = 0; m < 2; ++m)
#pragma unroll
        for (int n = 0; n < 2; ++n)
          acc[m][n] = __builtin_amdgcn_mfma_f32_16x16x32_bf16(af[m], bg[n], acc[m][n], 0, 0, 0);
    }
    __syncthreads();
  }
#pragma unroll
  for (int m = 0; m < 2; ++m)
#pragma unroll
    for (int n = 0; n < 2; ++n)
#pragma unroll
      for (int r = 0; r < 4; ++r) {
        int lr = wm * 32 + m * 16 + kg * 4 + r;
        int lc = wn * 32 + n * 16 + fr;
        if (row0 + lr < n_e) {
          float v = acc[m][n][r] * s_wt[lr];
          atomicAdd(out + (size_t)s_tok[lr] * HH + n0 + lc, v);
        }
      }
}

extern "C" void kernel_launch(void* const* d_in, const int* in_sizes, int n_in,
                              void* d_out, int out_size, void* d_ws, size_t ws_size,
                              hipStream_t stream) {
  const float* x  = (const float*)d_in[0];
  const float* gw = (const float*)d_in[1];
  const float* w1 = (const float*)d_in[2];
  const float* w2 = (const float*)d_in[3];
  float* out = (float*)d_out;

  char* ws = (char*)d_ws;
  int*   tk_id    = (int*)(ws);
  float* tk_w     = (float*)(ws + 16384);
  int*   counts   = (int*)(ws + 32768);
  int*   cursor   = (int*)(ws + 32800);
  int*   offsets  = (int*)(ws + 32832);
  int*   tok_list = (int*)(ws + 33024);
  float* wt_list  = (float*)(ws + 49408);

  u16* xg    = (u16*)(ws + (1u << 20));   // [4224][2048] bf16
  u16* midBp = (u16*)(ws + (20u << 20));  // [4224][1408] bf16
  u16* w1b   = (u16*)(ws + (33u << 20));  // [8][1408][2048] bf16 (N-major)
  u16* w2b   = (u16*)(ws + 80740352u);    // [8][2048][1408] bf16 (N-major)
  const size_t NEED = 126877696u;

  zero_kernel<<<1024, 256, 0, stream>>>((float4*)out, TT * HH / 4, counts);
  router_kernel<<<TT, 64, 0, stream>>>(x, gw, tk_id, tk_w, counts);
  scan_kernel<<<1, 64, 0, stream>>>(counts, offsets, cursor);
  assign_kernel<<<TT / 256, 256, 0, stream>>>(tk_id, tk_w, offsets, cursor, tok_list, wt_list);

  if (ws_size >= NEED) {
    gather_x_kernel<<<2 * TT, 256, 0, stream>>>(x, tok_list, xg);
    convtrans_kernel<<<dim3(II / 64, HH / 64, EE), 256, 0, stream>>>(w1, w1b, HH, II);
    convtrans_kernel<<<dim3(HH / 64, II / 64, EE), 256, 0, stream>>>(w2, w2b, II, HH);
    // gemm1: 128x64 tiles, no K-split -> 704 real blocks, silu fused, 24KB LDS
    moe_gemm<64, HH, 1, 0><<<dim3(EE, II / 64, 16), 256, 0, stream>>>(
        xg, w1b, tok_list, wt_list, offsets, midBp, out);
    // gemm2: 128x128 tiles, K-split x2 -> 1024 real blocks, atomic epilogue, 33KB LDS
    moe_gemm<128, II, 2, 2><<<dim3(EE, 2 * (HH / 128), 16), 256, 0, stream>>>(
        midBp, w2b, tok_list, wt_list, offsets, midBp, out);
  } else {
    u16* mid0 = (u16*)(ws + 131072);
    gemm1_small<<<dim3(II / 64, TT / 64, EE), 256, 0, stream>>>(x, w1, tok_list, offsets, mid0);
    gemm2_small<<<dim3(HH / 64, TT / 64, EE), 256, 0, stream>>>(mid0, w2, tok_list, wt_list, offsets, out);
  }
}

// Round 6
// 279.380 us; speedup vs baseline: 1.1449x; 1.0206x over previous
//
#include <hip/hip_runtime.h>
#include <hip/hip_bf16.h>
#include <math.h>

#define TT 2048
#define HH 2048
#define EE 8
#define II 1408

typedef short bf16x8 __attribute__((ext_vector_type(8)));
typedef float f32x4 __attribute__((ext_vector_type(4)));
typedef unsigned int u32;
typedef unsigned short u16;

__device__ __forceinline__ u16 f2bf(float f) {
  union { float f; u32 u; } v; v.f = f;
  u32 r = v.u + 0x7fffu + ((v.u >> 16) & 1u);
  return (u16)(r >> 16);
}

__device__ __forceinline__ void gload16(const void* g, void* l) {
  __builtin_amdgcn_global_load_lds((const __attribute__((address_space(1))) u32*)g,
                                   (__attribute__((address_space(3))) u32*)l, 16, 0, 0);
}

// ---------------- zero out + counters ----------------
__global__ void zero_kernel(float4* __restrict__ out4, int n4, int* __restrict__ counts) {
  int i = blockIdx.x * blockDim.x + threadIdx.x;
  int stride = gridDim.x * blockDim.x;
  float4 z; z.x = 0.f; z.y = 0.f; z.z = 0.f; z.w = 0.f;
  for (int j = i; j < n4; j += stride) out4[j] = z;
  if (blockIdx.x == 0 && threadIdx.x < 2 * EE) counts[threadIdx.x] = 0;
}

// ---------------- router ----------------
__global__ void router_kernel(const float* __restrict__ x, const float* __restrict__ gw,
                              int* __restrict__ tk_id, float* __restrict__ tk_w,
                              int* __restrict__ counts) {
  int t = blockIdx.x;
  int lane = threadIdx.x;
  float acc[EE];
#pragma unroll
  for (int e = 0; e < EE; ++e) acc[e] = 0.f;
  const float* xr = x + (size_t)t * HH;
  for (int h = lane; h < HH; h += 64) {
    float xv = xr[h];
    const float* g = gw + (size_t)h * EE;
#pragma unroll
    for (int e = 0; e < EE; ++e) acc[e] += xv * g[e];
  }
#pragma unroll
  for (int off = 32; off > 0; off >>= 1) {
#pragma unroll
    for (int e = 0; e < EE; ++e) acc[e] += __shfl_down(acc[e], off, 64);
  }
  if (lane == 0) {
    int i0 = 0;
#pragma unroll
    for (int e = 1; e < EE; ++e) if (acc[e] > acc[i0]) i0 = e;
    int i1 = (i0 == 0) ? 1 : 0;
#pragma unroll
    for (int e = 0; e < EE; ++e) { if (e == i0) continue; if (acc[e] > acc[i1]) i1 = e; }
    float d = acc[i1] - acc[i0];
    float p1 = expf(d);
    float w0 = 1.f / (1.f + p1);
    float w1v = p1 * w0;
    tk_id[2 * t] = i0; tk_id[2 * t + 1] = i1;
    tk_w[2 * t] = w0;  tk_w[2 * t + 1] = w1v;
    atomicAdd(&counts[i0], 1);
    atomicAdd(&counts[i1], 1);
  }
}

// ---------------- scan ----------------
__global__ void scan_kernel(const int* __restrict__ counts, int* __restrict__ offsets,
                            int* __restrict__ cursor) {
  if (threadIdx.x == 0) {
    int s = 0;
    for (int e = 0; e < EE; ++e) { offsets[e] = s; s += counts[e]; cursor[e] = 0; }
    offsets[EE] = s;
  }
}

// ---------------- assign ----------------
__global__ void assign_kernel(const int* __restrict__ tk_id, const float* __restrict__ tk_w,
                              const int* __restrict__ offsets, int* __restrict__ cursor,
                              int* __restrict__ tok_list, float* __restrict__ wt_list) {
  int t = blockIdx.x * blockDim.x + threadIdx.x;
  if (t >= TT) return;
#pragma unroll
  for (int k = 0; k < 2; ++k) {
    int e = tk_id[2 * t + k];
    int p = atomicAdd(&cursor[e], 1);
    int slot = offsets[e] + p;
    tok_list[slot] = t;
    wt_list[slot] = tk_w[2 * t + k];
  }
}

// ---------------- gather x -> bf16 xg[slot][H] ----------------
__global__ void gather_x_kernel(const float* __restrict__ x, const int* __restrict__ tok_list,
                                u16* __restrict__ xg) {
  int slot = blockIdx.x;
  int tok = tok_list[slot];
  int c = threadIdx.x * 8;
  float4 v0 = *(const float4*)(x + (size_t)tok * HH + c);
  float4 v1 = *(const float4*)(x + (size_t)tok * HH + c + 4);
  u16 o[8] = { f2bf(v0.x), f2bf(v0.y), f2bf(v0.z), f2bf(v0.w),
               f2bf(v1.x), f2bf(v1.y), f2bf(v1.z), f2bf(v1.w) };
  *(uint4*)(xg + (size_t)slot * HH + c) = *(uint4*)o;
}

// ---------------- convert + transpose: w[e][K][N] fp32 -> wb[e][N][K] bf16 ----------------
__global__ void convtrans_kernel(const float* __restrict__ w, u16* __restrict__ wb,
                                 int K, int N) {
  int e = blockIdx.z;
  int n0 = blockIdx.x * 64, k0 = blockIdx.y * 64;
  __shared__ u16 sT[64][72];
  const float* we = w + (size_t)e * K * N;
  u16* wbe = wb + (size_t)e * K * N;
  int tid = threadIdx.x;
  int kl = tid >> 4, n4 = tid & 15;
#pragma unroll
  for (int j = 0; j < 4; ++j) {
    int k = kl + j * 16;
    float4 v = *(const float4*)(we + (size_t)(k0 + k) * N + n0 + n4 * 4);
    sT[n4 * 4 + 0][k] = f2bf(v.x);
    sT[n4 * 4 + 1][k] = f2bf(v.y);
    sT[n4 * 4 + 2][k] = f2bf(v.z);
    sT[n4 * 4 + 3][k] = f2bf(v.w);
  }
  __syncthreads();
  int nl = tid >> 3, kc = tid & 7;
#pragma unroll
  for (int j = 0; j < 2; ++j) {
    int n = nl + j * 32;
    uint4 v = *(const uint4*)(&sT[n][kc * 8]);
    *(uint4*)(wbe + (size_t)(n0 + n) * K + k0 + kc * 8) = v;
  }
}

// ---------------- grouped GEMM, 64x64x64 tiles, single-buffer, high block count ----------------
// A: [slot][KDIM] bf16; B: [e][Ndim][KDIM] bf16 (N-major).
// MODE 0: silu -> midB.  MODE 2: atomicAdd wt-scaled into out.
// Occupancy play: 16KB LDS, small acc -> many resident blocks/CU for TLP latency hiding.
template <int KDIM, int MODE>
__launch_bounds__(256)
__global__ void moe_gemm64(const u16* __restrict__ A, const u16* __restrict__ B,
                           const int* __restrict__ tok_list, const float* __restrict__ wt_list,
                           const int* __restrict__ offsets,
                           u16* __restrict__ midB, float* __restrict__ out) {
  constexpr int Ndim = (MODE == 2) ? HH : II;
  constexpr int NT = KDIM / 64;

  int e = blockIdx.z;
  int g_off = offsets[e];
  int n_e = offsets[e + 1] - g_off;
  int row0 = blockIdx.y * 64;
  if (row0 >= n_e) return;
  int n0 = blockIdx.x * 64;

  __shared__ u16 sA[64][64];
  __shared__ u16 sB[64][64];
  __shared__ int s_tok[64];
  __shared__ float s_wt[64];

  int tid = threadIdx.x;
  int lane = tid & 63, wv = tid >> 6;
  int wm = wv >> 1, wn = wv & 1;
  int fr = lane & 15, kg = lane >> 4;

  if constexpr (MODE == 2) {
    if (tid < 64) {
      int r = row0 + tid;
      int cr = r < n_e ? r : n_e - 1;
      s_tok[tid] = tok_list[g_off + cr];
      s_wt[tid] = wt_list[g_off + cr];
    }
  }

  // staging: 8 chunks of (8 rows x 64 cols) per operand; wave stages 2 A + 2 B chunks.
  // lane l writes 16B at chunk base + l*16; global source col pre-swizzled (XOR involution).
  int rA = lane >> 3;
  int colsw = ((lane & 7) ^ rA) * 8;
  const u16* Abase = A + (size_t)(g_off + row0 + rA) * KDIM + colsw;
  const u16* Bbase = B + (size_t)e * (size_t)Ndim * KDIM + (size_t)(n0 + rA) * KDIM + colsw;

  f32x4 acc[2][2];
#pragma unroll
  for (int m = 0; m < 2; ++m)
#pragma unroll
    for (int n = 0; n < 2; ++n)
      acc[m][n] = (f32x4){0.f, 0.f, 0.f, 0.f};

  for (int t = 0; t < NT; ++t) {
    int kof = t * 64;
#pragma unroll
    for (int j = 0; j < 2; ++j) {
      int c = wv * 2 + j;
      gload16(Abase + (size_t)c * 8 * KDIM + kof, &sA[c * 8][0]);
      gload16(Bbase + (size_t)c * 8 * KDIM + kof, &sB[c * 8][0]);
    }
    __syncthreads();   // drains vmcnt; tile landed
#pragma unroll
    for (int kh = 0; kh < 2; ++kh) {
      bf16x8 af[2], bg[2];
      int cbyte = (kh * 64 + kg * 16) ^ ((fr & 7) << 4);
#pragma unroll
      for (int m = 0; m < 2; ++m)
        af[m] = *(const bf16x8*)((const char*)&sA[0][0] + (wm * 32 + m * 16 + fr) * 128 + cbyte);
#pragma unroll
      for (int n = 0; n < 2; ++n)
        bg[n] = *(const bf16x8*)((const char*)&sB[0][0] + (wn * 32 + n * 16 + fr) * 128 + cbyte);
#pragma unroll
      for (int m = 0; m < 2; ++m)
#pragma unroll
        for (int n = 0; n < 2; ++n)
          acc[m][n] = __builtin_amdgcn_mfma_f32_16x16x32_bf16(af[m], bg[n], acc[m][n], 0, 0, 0);
    }
    __syncthreads();   // all waves done reading; safe to restage
  }

#pragma unroll
  for (int m = 0; m < 2; ++m) {
    int lr = wm * 32 + m * 16 + kg * 4;
#pragma unroll
    for (int n = 0; n < 2; ++n) {
      int lc = wn * 32 + n * 16 + fr;
#pragma unroll
      for (int r = 0; r < 4; ++r) {
        int rr = lr + r;
        if (row0 + rr < n_e) {
          if constexpr (MODE == 0) {
            float v = acc[m][n][r];
            float s = v / (1.f + expf(-v));
            midB[(size_t)(g_off + row0 + rr) * II + n0 + lc] = f2bf(s);
          } else {
            float v = acc[m][n][r] * s_wt[rr];
            atomicAdd(out + (size_t)s_tok[rr] * HH + n0 + lc, v);
          }
        }
      }
    }
  }
}

// ================= small fallback (round-1, proven; used only if ws too small) ===========
__launch_bounds__(256, 2)
__global__ void gemm1_small(const float* __restrict__ x, const float* __restrict__ w1,
                            const int* __restrict__ tok_list, const int* __restrict__ offsets,
                            u16* __restrict__ mid) {
  int e = blockIdx.z;
  int g_off = offsets[e];
  int n_e = offsets[e + 1] - g_off;
  int row0 = blockIdx.y * 64;
  if (row0 >= n_e) return;
  int n0 = blockIdx.x * 64;
  __shared__ u16 sA[64][72];
  __shared__ u16 sB[64][72];
  __shared__ int s_tok[64];
  int tid = threadIdx.x;
  if (tid < 64) {
    int r = row0 + tid;
    s_tok[tid] = tok_list[g_off + ((r < n_e) ? r : (n_e - 1))];
  }
  __syncthreads();
  int lane = tid & 63;
  int wv = tid >> 6;
  int wm = wv >> 1, wn = wv & 1;
  int fr = lane & 15, kg = lane >> 4;
  f32x4 acc[2][2];
#pragma unroll
  for (int i = 0; i < 2; ++i)
#pragma unroll
    for (int j = 0; j < 2; ++j) acc[i][j] = (f32x4){0.f, 0.f, 0.f, 0.f};
  const float* w1e = w1 + (size_t)e * HH * II;
  for (int k0 = 0; k0 < HH; k0 += 64) {
#pragma unroll
    for (int i = 0; i < 4; ++i) {
      int idx = tid + i * 256;
      int r = idx >> 4, c4 = idx & 15;
      float4 v = *(const float4*)(x + (size_t)s_tok[r] * HH + k0 + c4 * 4);
      unsigned long long pk = (unsigned long long)f2bf(v.x)
                            | ((unsigned long long)f2bf(v.y) << 16)
                            | ((unsigned long long)f2bf(v.z) << 32)
                            | ((unsigned long long)f2bf(v.w) << 48);
      *(unsigned long long*)(&sA[r][c4 * 4]) = pk;
    }
#pragma unroll
    for (int i = 0; i < 4; ++i) {
      int idx = tid + i * 256;
      int kk = idx >> 4, c4 = idx & 15;
      float4 v = *(const float4*)(w1e + (size_t)(k0 + kk) * II + n0 + c4 * 4);
      sB[c4 * 4 + 0][kk] = f2bf(v.x);
      sB[c4 * 4 + 1][kk] = f2bf(v.y);
      sB[c4 * 4 + 2][kk] = f2bf(v.z);
      sB[c4 * 4 + 3][kk] = f2bf(v.w);
    }
    __syncthreads();
#pragma unroll
    for (int kk = 0; kk < 64; kk += 32) {
      bf16x8 af[2], bg[2];
#pragma unroll
      for (int m = 0; m < 2; ++m) af[m] = *(const bf16x8*)(&sA[wm * 32 + m * 16 + fr][kk + kg * 8]);
#pragma unroll
      for (int n = 0; n < 2; ++n) bg[n] = *(const bf16x8*)(&sB[wn * 32 + n * 16 + fr][kk + kg * 8]);
#pragma unroll
      for (int m = 0; m < 2; ++m)
#pragma unroll
        for (int n = 0; n < 2; ++n)
          acc[m][n] = __builtin_amdgcn_mfma_f32_16x16x32_bf16(af[m], bg[n], acc[m][n], 0, 0, 0);
    }
    __syncthreads();
  }
#pragma unroll
  for (int m = 0; m < 2; ++m)
#pragma unroll
    for (int n = 0; n < 2; ++n)
#pragma unroll
      for (int r = 0; r < 4; ++r) {
        int lr = wm * 32 + m * 16 + kg * 4 + r;
        int lc = wn * 32 + n * 16 + fr;
        if (row0 + lr < n_e) {
          float v = acc[m][n][r];
          float s = v / (1.f + expf(-v));
          mid[(size_t)(g_off + row0 + lr) * II + n0 + lc] = f2bf(s);
        }
      }
}

__launch_bounds__(256, 2)
__global__ void gemm2_small(const u16* __restrict__ mid, const float* __restrict__ w2,
                            const int* __restrict__ tok_list, const float* __restrict__ wt_list,
                            const int* __restrict__ offsets, float* __restrict__ out) {
  int e = blockIdx.z;
  int g_off = offsets[e];
  int n_e = offsets[e + 1] - g_off;
  int row0 = blockIdx.y * 64;
  if (row0 >= n_e) return;
  int n0 = blockIdx.x * 64;
  __shared__ u16 sA[64][72];
  __shared__ u16 sB[64][72];
  __shared__ int s_tok[64];
  __shared__ float s_wt[64];
  int tid = threadIdx.x;
  if (tid < 64) {
    int r = row0 + tid;
    int cr = (r < n_e) ? r : (n_e - 1);
    s_tok[tid] = tok_list[g_off + cr];
    s_wt[tid] = wt_list[g_off + cr];
  }
  __syncthreads();
  int lane = tid & 63;
  int wv = tid >> 6;
  int wm = wv >> 1, wn = wv & 1;
  int fr = lane & 15, kg = lane >> 4;
  f32x4 acc[2][2];
#pragma unroll
  for (int i = 0; i < 2; ++i)
#pragma unroll
    for (int j = 0; j < 2; ++j) acc[i][j] = (f32x4){0.f, 0.f, 0.f, 0.f};
  const float* w2e = w2 + (size_t)e * II * HH;
  for (int k0 = 0; k0 < II; k0 += 64) {
#pragma unroll
    for (int i = 0; i < 2; ++i) {
      int idx = tid + i * 256;
      int r = idx >> 3, c8 = idx & 7;
      int gr = row0 + r; if (gr >= n_e) gr = n_e - 1;
      uint4 v = *(const uint4*)(mid + (size_t)(g_off + gr) * II + k0 + c8 * 8);
      *(uint4*)(&sA[r][c8 * 8]) = v;
    }
#pragma unroll
    for (int i = 0; i < 4; ++i) {
      int idx = tid + i * 256;
      int kk = idx >> 4, c4 = idx & 15;
      float4 v = *(const float4*)(w2e + (size_t)(k0 + kk) * HH + n0 + c4 * 4);
      sB[c4 * 4 + 0][kk] = f2bf(v.x);
      sB[c4 * 4 + 1][kk] = f2bf(v.y);
      sB[c4 * 4 + 2][kk] = f2bf(v.z);
      sB[c4 * 4 + 3][kk] = f2bf(v.w);
    }
    __syncthreads();
#pragma unroll
    for (int kk = 0; kk < 64; kk += 32) {
      bf16x8 af[2], bg[2];
#pragma unroll
      for (int m = 0; m < 2; ++m) af[m] = *(const bf16x8*)(&sA[wm * 32 + m * 16 + fr][kk + kg * 8]);
#pragma unroll
      for (int n = 0; n < 2; ++n) bg[n] = *(const bf16x8*)(&sB[wn * 32 + n * 16 + fr][kk + kg * 8]);
#pragma unroll
      for (int m = 0; m < 2; ++m)
#pragma unroll
        for (int n = 0; n < 2; ++n)
          acc[m][n] = __builtin_amdgcn_mfma_f32_16x16x32_bf16(af[m], bg[n], acc[m][n], 0, 0, 0);
    }
    __syncthreads();
  }
#pragma unroll
  for (int m = 0; m < 2; ++m)
#pragma unroll
    for (int n = 0; n < 2; ++n)
#pragma unroll
      for (int r = 0; r < 4; ++r) {
        int lr = wm * 32 + m * 16 + kg * 4 + r;
        int lc = wn * 32 + n * 16 + fr;
        if (row0 + lr < n_e) {
          float v = acc[m][n][r] * s_wt[lr];
          atomicAdd(out + (size_t)s_tok[lr] * HH + n0 + lc, v);
        }
      }
}

extern "C" void kernel_launch(void* const* d_in, const int* in_sizes, int n_in,
                              void* d_out, int out_size, void* d_ws, size_t ws_size,
                              hipStream_t stream) {
  const float* x  = (const float*)d_in[0];
  const float* gw = (const float*)d_in[1];
  const float* w1 = (const float*)d_in[2];
  const float* w2 = (const float*)d_in[3];
  float* out = (float*)d_out;

  char* ws = (char*)d_ws;
  int*   tk_id    = (int*)(ws);
  float* tk_w     = (float*)(ws + 16384);
  int*   counts   = (int*)(ws + 32768);
  int*   cursor   = (int*)(ws + 32800);
  int*   offsets  = (int*)(ws + 32832);
  int*   tok_list = (int*)(ws + 33024);
  float* wt_list  = (float*)(ws + 49408);

  u16* xg    = (u16*)(ws + (1u << 20));   // [4224][2048] bf16
  u16* midBp = (u16*)(ws + (20u << 20));  // [4224][1408] bf16
  u16* w1b   = (u16*)(ws + (33u << 20));  // [8][1408][2048] bf16 (N-major)
  u16* w2b   = (u16*)(ws + 80740352u);    // [8][2048][1408] bf16 (N-major)
  const size_t NEED = 126877696u;

  zero_kernel<<<1024, 256, 0, stream>>>((float4*)out, TT * HH / 4, counts);
  router_kernel<<<TT, 64, 0, stream>>>(x, gw, tk_id, tk_w, counts);
  scan_kernel<<<1, 64, 0, stream>>>(counts, offsets, cursor);
  assign_kernel<<<TT / 256, 256, 0, stream>>>(tk_id, tk_w, offsets, cursor, tok_list, wt_list);

  if (ws_size >= NEED) {
    gather_x_kernel<<<2 * TT, 256, 0, stream>>>(x, tok_list, xg);
    convtrans_kernel<<<dim3(II / 64, HH / 64, EE), 256, 0, stream>>>(w1, w1b, HH, II);
    convtrans_kernel<<<dim3(HH / 64, II / 64, EE), 256, 0, stream>>>(w2, w2b, II, HH);
    // gemm1: 64x64 tiles -> 1408 real blocks (5.5/CU), silu fused
    moe_gemm64<HH, 0><<<dim3(II / 64, TT / 64, EE), 256, 0, stream>>>(
        xg, w1b, tok_list, wt_list, offsets, midBp, out);
    // gemm2: 64x64 tiles -> 2048 real blocks (8/CU), atomic scatter epilogue
    moe_gemm64<II, 2><<<dim3(HH / 64, TT / 64, EE), 256, 0, stream>>>(
        midBp, w2b, tok_list, wt_list, offsets, midBp, out);
  } else {
    u16* mid0 = (u16*)(ws + 131072);
    gemm1_small<<<dim3(II / 64, TT / 64, EE), 256, 0, stream>>>(x, w1, tok_list, offsets, mid0);
    gemm2_small<<<dim3(HH / 64, TT / 64, EE), 256, 0, stream>>>(mid0, w2, tok_list, wt_list, offsets, out);
  }
}

// Round 7
// 226.320 us; speedup vs baseline: 1.4133x; 1.2344x over previous
//
#include <hip/hip_runtime.h>
#include <hip/hip_bf16.h>
#include <math.h>

#define TT 2048
#define HH 2048
#define EE 8
#define II 1408

typedef short bf16x8 __attribute__((ext_vector_type(8)));
typedef float f32x4 __attribute__((ext_vector_type(4)));
typedef unsigned int u32;
typedef unsigned short u16;

__device__ __forceinline__ u16 f2bf(float f) {
  union { float f; u32 u; } v; v.f = f;
  u32 r = v.u + 0x7fffu + ((v.u >> 16) & 1u);
  return (u16)(r >> 16);
}

__device__ __forceinline__ void gload16(const void* g, void* l) {
  __builtin_amdgcn_global_load_lds((const __attribute__((address_space(1))) u32*)g,
                                   (__attribute__((address_space(3))) u32*)l, 16, 0, 0);
}

// ---------------- router: logits -> top2 (no counts) ----------------
__global__ void router_kernel(const float* __restrict__ x, const float* __restrict__ gw,
                              int* __restrict__ tk_id, float* __restrict__ tk_w) {
  int t = blockIdx.x;
  int lane = threadIdx.x;
  float acc[EE];
#pragma unroll
  for (int e = 0; e < EE; ++e) acc[e] = 0.f;
  const float* xr = x + (size_t)t * HH;
  for (int h = lane; h < HH; h += 64) {
    float xv = xr[h];
    const float* g = gw + (size_t)h * EE;
#pragma unroll
    for (int e = 0; e < EE; ++e) acc[e] += xv * g[e];
  }
#pragma unroll
  for (int off = 32; off > 0; off >>= 1) {
#pragma unroll
    for (int e = 0; e < EE; ++e) acc[e] += __shfl_down(acc[e], off, 64);
  }
  if (lane == 0) {
    int i0 = 0;
#pragma unroll
    for (int e = 1; e < EE; ++e) if (acc[e] > acc[i0]) i0 = e;
    int i1 = (i0 == 0) ? 1 : 0;
#pragma unroll
    for (int e = 0; e < EE; ++e) { if (e == i0) continue; if (acc[e] > acc[i1]) i1 = e; }
    float d = acc[i1] - acc[i0];
    float p1 = expf(d);
    float w0 = 1.f / (1.f + p1);
    float w1v = p1 * w0;
    tk_id[2 * t] = i0; tk_id[2 * t + 1] = i1;
    tk_w[2 * t] = w0;  tk_w[2 * t + 1] = w1v;
  }
}

// ---------------- count + scan + assign, one block ----------------
__global__ void scanassign_kernel(const int* __restrict__ tk_id, const float* __restrict__ tk_w,
                                  int* __restrict__ offsets, int* __restrict__ tok_list,
                                  float* __restrict__ wt_list, int* __restrict__ islot) {
  __shared__ int s_cnt[EE];
  __shared__ int s_off[EE + 1];
  __shared__ int s_cur[EE];
  int tid = threadIdx.x;
  if (tid < EE) { s_cnt[tid] = 0; s_cur[tid] = 0; }
  __syncthreads();
  for (int i = tid; i < 2 * TT; i += 256) atomicAdd(&s_cnt[tk_id[i]], 1);
  __syncthreads();
  if (tid == 0) {
    int s = 0;
    for (int e = 0; e < EE; ++e) { s_off[e] = s; s += s_cnt[e]; }
    s_off[EE] = s;
    for (int e = 0; e <= EE; ++e) offsets[e] = s_off[e];
  }
  __syncthreads();
  for (int t = tid; t < TT; t += 256) {
#pragma unroll
    for (int k = 0; k < 2; ++k) {
      int e = tk_id[2 * t + k];
      int p = atomicAdd(&s_cur[e], 1);
      int slot = s_off[e] + p;
      tok_list[slot] = t;
      wt_list[slot] = tk_w[2 * t + k];
      islot[2 * t + k] = slot;
    }
  }
}

// ---------------- gather x -> bf16 xg[slot][H] ----------------
__global__ void gather_x_kernel(const float* __restrict__ x, const int* __restrict__ tok_list,
                                u16* __restrict__ xg) {
  int slot = blockIdx.x;
  int tok = tok_list[slot];
  int c = threadIdx.x * 8;
  float4 v0 = *(const float4*)(x + (size_t)tok * HH + c);
  float4 v1 = *(const float4*)(x + (size_t)tok * HH + c + 4);
  u16 o[8] = { f2bf(v0.x), f2bf(v0.y), f2bf(v0.z), f2bf(v0.w),
               f2bf(v1.x), f2bf(v1.y), f2bf(v1.z), f2bf(v1.w) };
  *(uint4*)(xg + (size_t)slot * HH + c) = *(uint4*)o;
}

// ---------------- convert + transpose: w[e][K][N] fp32 -> wb[e][N][K] bf16 ----------------
__global__ void convtrans_kernel(const float* __restrict__ w, u16* __restrict__ wb,
                                 int K, int N) {
  int e = blockIdx.z;
  int n0 = blockIdx.x * 64, k0 = blockIdx.y * 64;
  __shared__ u16 sT[64][72];
  const float* we = w + (size_t)e * K * N;
  u16* wbe = wb + (size_t)e * K * N;
  int tid = threadIdx.x;
  int kl = tid >> 4, n4 = tid & 15;
#pragma unroll
  for (int j = 0; j < 4; ++j) {
    int k = kl + j * 16;
    float4 v = *(const float4*)(we + (size_t)(k0 + k) * N + n0 + n4 * 4);
    sT[n4 * 4 + 0][k] = f2bf(v.x);
    sT[n4 * 4 + 1][k] = f2bf(v.y);
    sT[n4 * 4 + 2][k] = f2bf(v.z);
    sT[n4 * 4 + 3][k] = f2bf(v.w);
  }
  __syncthreads();
  int nl = tid >> 3, kc = tid & 7;
#pragma unroll
  for (int j = 0; j < 2; ++j) {
    int n = nl + j * 32;
    uint4 v = *(const uint4*)(&sT[n][kc * 8]);
    *(uint4*)(wbe + (size_t)(n0 + n) * K + k0 + kc * 8) = v;
  }
}

// ---------------- combine: out[t] = w0*y[s0] + w1*y[s1] ----------------
__global__ void combine_kernel(const float* __restrict__ y, const int* __restrict__ islot,
                               const float* __restrict__ tk_w, float* __restrict__ out) {
  int t = blockIdx.x;
  int h = threadIdx.x * 8;
  int s0 = islot[2 * t], s1 = islot[2 * t + 1];
  float w0 = tk_w[2 * t], w1 = tk_w[2 * t + 1];
  const float* y0 = y + (size_t)s0 * HH + h;
  const float* y1 = y + (size_t)s1 * HH + h;
  float* op = out + (size_t)t * HH + h;
  float4 a0 = *(const float4*)(y0);
  float4 a1 = *(const float4*)(y0 + 4);
  float4 b0 = *(const float4*)(y1);
  float4 b1 = *(const float4*)(y1 + 4);
  float4 r0, r1;
  r0.x = w0 * a0.x + w1 * b0.x; r0.y = w0 * a0.y + w1 * b0.y;
  r0.z = w0 * a0.z + w1 * b0.z; r0.w = w0 * a0.w + w1 * b0.w;
  r1.x = w0 * a1.x + w1 * b1.x; r1.y = w0 * a1.y + w1 * b1.y;
  r1.z = w0 * a1.z + w1 * b1.z; r1.w = w0 * a1.w + w1 * b1.w;
  *(float4*)(op) = r0;
  *(float4*)(op + 4) = r1;
}

// ---------------- grouped GEMM, 64x64x64, 3-buffer 1-barrier pipeline ----------------
// A: [slot][KDIM] bf16; B: [e][Ndim][KDIM] bf16 (N-major).
// MODE 0: silu -> midB bf16.  MODE 2: dense fp32 y[slot][HH] (no atomics).
// stage(t+1) issued BEFORE compute(t); the single vmcnt(0)+barrier at loop end
// drains loads that had the whole compute phase to land. Buffer written at t was
// last read at t-2 (two barriers back) -> safe with one barrier per step.
template <int KDIM, int MODE>
__launch_bounds__(256)
__global__ void moe_gemm64(const u16* __restrict__ A, const u16* __restrict__ B,
                           const int* __restrict__ offsets,
                           u16* __restrict__ midB, float* __restrict__ y) {
  constexpr int Ndim = (MODE == 2) ? HH : II;
  constexpr int NT = KDIM / 64;

  int e = blockIdx.z;
  int g_off = offsets[e];
  int n_e = offsets[e + 1] - g_off;
  int row0 = blockIdx.y * 64;
  if (row0 >= n_e) return;
  int n0 = blockIdx.x * 64;

  __shared__ u16 sA[3][64][64];
  __shared__ u16 sB[3][64][64];

  int tid = threadIdx.x;
  int lane = tid & 63, wv = tid >> 6;
  int wm = wv >> 1, wn = wv & 1;
  int fr = lane & 15, kg = lane >> 4;

  // staging: 8 chunks of (8 rows x 64 cols) per operand; wave stages 2 A + 2 B chunks.
  // lane l writes 16B at chunk base + l*16; global source col pre-swizzled (XOR involution).
  int rA = lane >> 3;
  int colsw = ((lane & 7) ^ rA) * 8;
  const u16* Abase = A + (size_t)(g_off + row0 + rA) * KDIM + colsw;
  const u16* Bbase = B + (size_t)e * (size_t)Ndim * KDIM + (size_t)(n0 + rA) * KDIM + colsw;

  f32x4 acc[2][2];
#pragma unroll
  for (int m = 0; m < 2; ++m)
#pragma unroll
    for (int n = 0; n < 2; ++n)
      acc[m][n] = (f32x4){0.f, 0.f, 0.f, 0.f};

  auto stage = [&](int buf, int t) {
    int kof = t * 64;
#pragma unroll
    for (int j = 0; j < 2; ++j) {
      int c = wv * 2 + j;
      gload16(Abase + (size_t)c * 8 * KDIM + kof, &sA[buf][c * 8][0]);
      gload16(Bbase + (size_t)c * 8 * KDIM + kof, &sB[buf][c * 8][0]);
    }
  };

  stage(0, 0);
  __syncthreads();           // tile 0 landed (compiler drains vmcnt before barrier)

  int cur = 0, nxt = 1;
  for (int t = 0; t < NT; ++t) {
    if (t + 1 < NT) stage(nxt, t + 1);   // issue next tile, overlaps with compute below
#pragma unroll
    for (int kh = 0; kh < 2; ++kh) {
      bf16x8 af[2], bg[2];
      int cbyte = (kh * 64 + kg * 16) ^ ((fr & 7) << 4);
#pragma unroll
      for (int m = 0; m < 2; ++m)
        af[m] = *(const bf16x8*)((const char*)&sA[cur][0][0] + (wm * 32 + m * 16 + fr) * 128 + cbyte);
#pragma unroll
      for (int n = 0; n < 2; ++n)
        bg[n] = *(const bf16x8*)((const char*)&sB[cur][0][0] + (wn * 32 + n * 16 + fr) * 128 + cbyte);
#pragma unroll
      for (int m = 0; m < 2; ++m)
#pragma unroll
        for (int n = 0; n < 2; ++n)
          acc[m][n] = __builtin_amdgcn_mfma_f32_16x16x32_bf16(af[m], bg[n], acc[m][n], 0, 0, 0);
    }
    __syncthreads();         // drains vmcnt(0): tile t+1 committed; everyone done reading cur
    cur = nxt; nxt = nxt + 1; if (nxt == 3) nxt = 0;
  }

#pragma unroll
  for (int m = 0; m < 2; ++m) {
    int lr = wm * 32 + m * 16 + kg * 4;
#pragma unroll
    for (int n = 0; n < 2; ++n) {
      int lc = wn * 32 + n * 16 + fr;
#pragma unroll
      for (int r = 0; r < 4; ++r) {
        int rr = lr + r;
        if (row0 + rr < n_e) {
          if constexpr (MODE == 0) {
            float v = acc[m][n][r];
            float s = v / (1.f + expf(-v));
            midB[(size_t)(g_off + row0 + rr) * II + n0 + lc] = f2bf(s);
          } else {
            y[(size_t)(g_off + row0 + rr) * HH + n0 + lc] = acc[m][n][r];
          }
        }
      }
    }
  }
}

// ================= fallback path (proven; used only if ws too small) ===========
__global__ void zero_kernel(float4* __restrict__ out4, int n4) {
  int i = blockIdx.x * blockDim.x + threadIdx.x;
  int stride = gridDim.x * blockDim.x;
  float4 z; z.x = 0.f; z.y = 0.f; z.z = 0.f; z.w = 0.f;
  for (int j = i; j < n4; j += stride) out4[j] = z;
}

__launch_bounds__(256, 2)
__global__ void gemm1_small(const float* __restrict__ x, const float* __restrict__ w1,
                            const int* __restrict__ tok_list, const int* __restrict__ offsets,
                            u16* __restrict__ mid) {
  int e = blockIdx.z;
  int g_off = offsets[e];
  int n_e = offsets[e + 1] - g_off;
  int row0 = blockIdx.y * 64;
  if (row0 >= n_e) return;
  int n0 = blockIdx.x * 64;
  __shared__ u16 sA[64][72];
  __shared__ u16 sB[64][72];
  __shared__ int s_tok[64];
  int tid = threadIdx.x;
  if (tid < 64) {
    int r = row0 + tid;
    s_tok[tid] = tok_list[g_off + ((r < n_e) ? r : (n_e - 1))];
  }
  __syncthreads();
  int lane = tid & 63;
  int wv = tid >> 6;
  int wm = wv >> 1, wn = wv & 1;
  int fr = lane & 15, kg = lane >> 4;
  f32x4 acc[2][2];
#pragma unroll
  for (int i = 0; i < 2; ++i)
#pragma unroll
    for (int j = 0; j < 2; ++j) acc[i][j] = (f32x4){0.f, 0.f, 0.f, 0.f};
  const float* w1e = w1 + (size_t)e * HH * II;
  for (int k0 = 0; k0 < HH; k0 += 64) {
#pragma unroll
    for (int i = 0; i < 4; ++i) {
      int idx = tid + i * 256;
      int r = idx >> 4, c4 = idx & 15;
      float4 v = *(const float4*)(x + (size_t)s_tok[r] * HH + k0 + c4 * 4);
      unsigned long long pk = (unsigned long long)f2bf(v.x)
                            | ((unsigned long long)f2bf(v.y) << 16)
                            | ((unsigned long long)f2bf(v.z) << 32)
                            | ((unsigned long long)f2bf(v.w) << 48);
      *(unsigned long long*)(&sA[r][c4 * 4]) = pk;
    }
#pragma unroll
    for (int i = 0; i < 4; ++i) {
      int idx = tid + i * 256;
      int kk = idx >> 4, c4 = idx & 15;
      float4 v = *(const float4*)(w1e + (size_t)(k0 + kk) * II + n0 + c4 * 4);
      sB[c4 * 4 + 0][kk] = f2bf(v.x);
      sB[c4 * 4 + 1][kk] = f2bf(v.y);
      sB[c4 * 4 + 2][kk] = f2bf(v.z);
      sB[c4 * 4 + 3][kk] = f2bf(v.w);
    }
    __syncthreads();
#pragma unroll
    for (int kk = 0; kk < 64; kk += 32) {
      bf16x8 af[2], bg[2];
#pragma unroll
      for (int m = 0; m < 2; ++m) af[m] = *(const bf16x8*)(&sA[wm * 32 + m * 16 + fr][kk + kg * 8]);
#pragma unroll
      for (int n = 0; n < 2; ++n) bg[n] = *(const bf16x8*)(&sB[wn * 32 + n * 16 + fr][kk + kg * 8]);
#pragma unroll
      for (int m = 0; m < 2; ++m)
#pragma unroll
        for (int n = 0; n < 2; ++n)
          acc[m][n] = __builtin_amdgcn_mfma_f32_16x16x32_bf16(af[m], bg[n], acc[m][n], 0, 0, 0);
    }
    __syncthreads();
  }
#pragma unroll
  for (int m = 0; m < 2; ++m)
#pragma unroll
    for (int n = 0; n < 2; ++n)
#pragma unroll
      for (int r = 0; r < 4; ++r) {
        int lr = wm * 32 + m * 16 + kg * 4 + r;
        int lc = wn * 32 + n * 16 + fr;
        if (row0 + lr < n_e) {
          float v = acc[m][n][r];
          float s = v / (1.f + expf(-v));
          mid[(size_t)(g_off + row0 + lr) * II + n0 + lc] = f2bf(s);
        }
      }
}

__launch_bounds__(256, 2)
__global__ void gemm2_small(const u16* __restrict__ mid, const float* __restrict__ w2,
                            const int* __restrict__ tok_list, const float* __restrict__ wt_list,
                            const int* __restrict__ offsets, float* __restrict__ out) {
  int e = blockIdx.z;
  int g_off = offsets[e];
  int n_e = offsets[e + 1] - g_off;
  int row0 = blockIdx.y * 64;
  if (row0 >= n_e) return;
  int n0 = blockIdx.x * 64;
  __shared__ u16 sA[64][72];
  __shared__ u16 sB[64][72];
  __shared__ int s_tok[64];
  __shared__ float s_wt[64];
  int tid = threadIdx.x;
  if (tid < 64) {
    int r = row0 + tid;
    int cr = (r < n_e) ? r : (n_e - 1);
    s_tok[tid] = tok_list[g_off + cr];
    s_wt[tid] = wt_list[g_off + cr];
  }
  __syncthreads();
  int lane = tid & 63;
  int wv = tid >> 6;
  int wm = wv >> 1, wn = wv & 1;
  int fr = lane & 15, kg = lane >> 4;
  f32x4 acc[2][2];
#pragma unroll
  for (int i = 0; i < 2; ++i)
#pragma unroll
    for (int j = 0; j < 2; ++j) acc[i][j] = (f32x4){0.f, 0.f, 0.f, 0.f};
  const float* w2e = w2 + (size_t)e * II * HH;
  for (int k0 = 0; k0 < II; k0 += 64) {
#pragma unroll
    for (int i = 0; i < 2; ++i) {
      int idx = tid + i * 256;
      int r = idx >> 3, c8 = idx & 7;
      int gr = row0 + r; if (gr >= n_e) gr = n_e - 1;
      uint4 v = *(const uint4*)(mid + (size_t)(g_off + gr) * II + k0 + c8 * 8);
      *(uint4*)(&sA[r][c8 * 8]) = v;
    }
#pragma unroll
    for (int i = 0; i < 4; ++i) {
      int idx = tid + i * 256;
      int kk = idx >> 4, c4 = idx & 15;
      float4 v = *(const float4*)(w2e + (size_t)(k0 + kk) * HH + n0 + c4 * 4);
      sB[c4 * 4 + 0][kk] = f2bf(v.x);
      sB[c4 * 4 + 1][kk] = f2bf(v.y);
      sB[c4 * 4 + 2][kk] = f2bf(v.z);
      sB[c4 * 4 + 3][kk] = f2bf(v.w);
    }
    __syncthreads();
#pragma unroll
    for (int kk = 0; kk < 64; kk += 32) {
      bf16x8 af[2], bg[2];
#pragma unroll
      for (int m = 0; m < 2; ++m) af[m] = *(const bf16x8*)(&sA[wm * 32 + m * 16 + fr][kk + kg * 8]);
#pragma unroll
      for (int n = 0; n < 2; ++n) bg[n] = *(const bf16x8*)(&sB[wn * 32 + n * 16 + fr][kk + kg * 8]);
#pragma unroll
      for (int m = 0; m < 2; ++m)
#pragma unroll
        for (int n = 0; n < 2; ++n)
          acc[m][n] = __builtin_amdgcn_mfma_f32_16x16x32_bf16(af[m], bg[n], acc[m][n], 0, 0, 0);
    }
    __syncthreads();
  }
#pragma unroll
  for (int m = 0; m < 2; ++m)
#pragma unroll
    for (int n = 0; n < 2; ++n)
#pragma unroll
      for (int r = 0; r < 4; ++r) {
        int lr = wm * 32 + m * 16 + kg * 4 + r;
        int lc = wn * 32 + n * 16 + fr;
        if (row0 + lr < n_e) {
          float v = acc[m][n][r] * s_wt[lr];
          atomicAdd(out + (size_t)s_tok[lr] * HH + n0 + lc, v);
        }
      }
}

extern "C" void kernel_launch(void* const* d_in, const int* in_sizes, int n_in,
                              void* d_out, int out_size, void* d_ws, size_t ws_size,
                              hipStream_t stream) {
  const float* x  = (const float*)d_in[0];
  const float* gw = (const float*)d_in[1];
  const float* w1 = (const float*)d_in[2];
  const float* w2 = (const float*)d_in[3];
  float* out = (float*)d_out;

  char* ws = (char*)d_ws;
  int*   tk_id    = (int*)(ws);
  float* tk_w     = (float*)(ws + 16384);
  int*   offsets  = (int*)(ws + 32832);
  int*   tok_list = (int*)(ws + 33024);
  float* wt_list  = (float*)(ws + 49408);
  int*   islot    = (int*)(ws + 65792);

  u16* xg    = (u16*)(ws + (1u << 20));   // [4224][2048] bf16
  u16* midBp = (u16*)(ws + (20u << 20));  // [4224][1408] bf16
  u16* w1b   = (u16*)(ws + (33u << 20));  // [8][1408][2048] bf16 (N-major); dead after gemm1
  u16* w2b   = (u16*)(ws + 80740352u);    // [8][2048][1408] bf16 (N-major)
  float* y   = (float*)(ws + (33u << 20)); // [4224][2048] f32, ALIASES w1b (dead after gemm1)
  const size_t NEED = 126877696u;

  router_kernel<<<TT, 64, 0, stream>>>(x, gw, tk_id, tk_w);
  scanassign_kernel<<<1, 256, 0, stream>>>(tk_id, tk_w, offsets, tok_list, wt_list, islot);

  if (ws_size >= NEED) {
    gather_x_kernel<<<2 * TT, 256, 0, stream>>>(x, tok_list, xg);
    convtrans_kernel<<<dim3(II / 64, HH / 64, EE), 256, 0, stream>>>(w1, w1b, HH, II);
    convtrans_kernel<<<dim3(HH / 64, II / 64, EE), 256, 0, stream>>>(w2, w2b, II, HH);
    // gemm1: 64x64, 3-buf 1-barrier, silu fused -> midBp
    moe_gemm64<HH, 0><<<dim3(II / 64, TT / 64, EE), 256, 0, stream>>>(
        xg, w1b, offsets, midBp, y);
    // gemm2: 64x64, 3-buf 1-barrier, dense fp32 y (no atomics; y overwrites w1b)
    moe_gemm64<II, 2><<<dim3(HH / 64, TT / 64, EE), 256, 0, stream>>>(
        midBp, w2b, offsets, midBp, y);
    // combine: out[t] = w0*y[s0] + w1*y[s1]  (fully overwrites out; no zero pass)
    combine_kernel<<<TT, 256, 0, stream>>>(y, islot, tk_w, out);
  } else {
    u16* mid0 = (u16*)(ws + 131072);
    zero_kernel<<<1024, 256, 0, stream>>>((float4*)out, TT * HH / 4);
    gemm1_small<<<dim3(II / 64, TT / 64, EE), 256, 0, stream>>>(x, w1, tok_list, offsets, mid0);
    gemm2_small<<<dim3(HH / 64, TT / 64, EE), 256, 0, stream>>>(mid0, w2, tok_list, wt_list, offsets, out);
  }
}